// Round 1
// baseline (412.969 us; speedup 1.0000x reference)
//
#include <hip/hip_runtime.h>
#include <math.h>

#define DEV_EPS 1e-5f

namespace {
constexpr int B_ = 16, C_ = 256, H_ = 56, W_ = 56, HW_ = H_ * W_;
constexpr int G_ = 16, GC_ = 16, RED_ = 64, KK_ = 49;
constexpr int NTOT = B_ * HW_;  // 50176 flattened (batch, pixel)

typedef __attribute__((ext_vector_type(8))) short short8;
typedef __attribute__((ext_vector_type(4))) float f32x4;

__device__ __forceinline__ unsigned short bf16r(float f) {
  unsigned u = __float_as_uint(f);
  u += 0x7fff + ((u >> 16) & 1);  // RNE
  return (unsigned short)(u >> 16);
}
__device__ __forceinline__ float bf2f(unsigned short s) {
  return __uint_as_float((unsigned)s << 16);
}

// async global->LDS, 16B per lane. LDS dest is wave-uniform base + lane*16
// (m104: no per-lane LDS scatter) — so any swizzle goes on the GLOBAL address.
__device__ __forceinline__ void gl_lds16(const void* g, void* l) {
  __builtin_amdgcn_global_load_lds(
      (const __attribute__((address_space(1))) unsigned int*)g,
      (__attribute__((address_space(3))) unsigned int*)l, 16, 0, 0);
}

// ---------------------------------------------------------------------------
// MFMA GEMM: D[m][n] = sum_k Wt[m][k] * Act[n][k]   (both bf16, k-contiguous)
// Block = 256 threads = 4 waves; wave tile 64x64; BM=WM*64, BN=WN*64, BK=64.
// LDS tiles [row][64k] bf16, 128B rows; global chunk q^(row&7) XOR-swizzle so
// frag ds_read_b128 is 2-way-only (free, m136).
// EPI: 0 = tanh(bn)->act_T bf16, 1 = relu(bn)->act_T bf16,
//      3 = bn + x skip -> planar fp32 [b][C][HW] (final out)
// ---------------------------------------------------------------------------
template <int WM, int WN, int KD, int EPI>
__global__ __launch_bounds__(256)
void mfma_gemm(const unsigned short* __restrict__ A,   // [M][KD] bf16
               const unsigned short* __restrict__ Act, // [NTOT][KD] bf16
               const float* __restrict__ p0,
               const float* __restrict__ bg, const float* __restrict__ bb,
               const float* __restrict__ bm, const float* __restrict__ bv,
               const float* __restrict__ xskip, void* __restrict__ outp,
               int M) {
  constexpr int BM = WM * 64, BN = WN * 64;
  __shared__ unsigned short At[BM * 64];
  __shared__ unsigned short Bt[BN * 64];
  __shared__ float aS[BM], bS[BM];

  const int tid = threadIdx.x;
  const int n0 = blockIdx.x * BN, m0 = blockIdx.y * BM;
  const int wave = tid >> 6, lane = tid & 63;
  const int wm = (WM == 2) ? (wave >> 1) : 0;
  const int wn = (WM == 2) ? (wave & 1) : wave;

  if (tid < BM) {
    int m = min(m0 + tid, M - 1);
    float sc = bg[m] * rsqrtf(bv[m] + DEV_EPS);
    aS[tid] = sc;
    bS[tid] = sc * p0[m] + bb[m] - bm[m] * sc;
  }

  f32x4 acc[4][4];
#pragma unroll
  for (int i = 0; i < 4; ++i)
#pragma unroll
    for (int j = 0; j < 4; ++j)
#pragma unroll
      for (int e = 0; e < 4; ++e) acc[i][j][e] = 0.f;

  const int lq = lane & 7;          // chunk slot within a row-octet
  const int lr8 = lane >> 3;        // row within octet group
  const int quad = lane >> 4, ln = lane & 15;

#pragma unroll 1
  for (int kt = 0; kt < KD / 64; ++kt) {
    __syncthreads();  // protect LDS from previous iteration's readers
    // stage A: BM rows x 64k; one instr = 8 rows (1KB)
#pragma unroll
    for (int t = 0; t < BM / 32; ++t) {
      int inst = wave * (BM / 32) + t;
      int row = inst * 8 + lr8;
      int mrow = min(m0 + row, M - 1);
      int qs = lq ^ (row & 7);
      gl_lds16(A + (size_t)mrow * KD + kt * 64 + qs * 8, &At[inst * 512]);
    }
    // stage B (activations)
#pragma unroll
    for (int t = 0; t < BN / 32; ++t) {
      int inst = wave * (BN / 32) + t;
      int row = inst * 8 + lr8;
      int qs = lq ^ (row & 7);
      gl_lds16(Act + (size_t)(n0 + row) * KD + kt * 64 + qs * 8, &Bt[inst * 512]);
    }
    __syncthreads();  // barrier drains vmcnt -> LDS tiles complete

#pragma unroll
    for (int s = 0; s < 2; ++s) {
      const int c = s * 4 + quad;
      short8 af[4], bf[4];
#pragma unroll
      for (int i = 0; i < 4; ++i) {
        int r = wm * 64 + i * 16 + ln;
        af[i] = *(const short8*)&At[r * 64 + (c ^ (r & 7)) * 8];
      }
#pragma unroll
      for (int j = 0; j < 4; ++j) {
        int r = wn * 64 + j * 16 + ln;
        bf[j] = *(const short8*)&Bt[r * 64 + (c ^ (r & 7)) * 8];
      }
#pragma unroll
      for (int i = 0; i < 4; ++i)
#pragma unroll
        for (int j = 0; j < 4; ++j)
          acc[i][j] = __builtin_amdgcn_mfma_f32_16x16x32_bf16(af[i], bf[j],
                                                              acc[i][j], 0, 0, 0);
    }
  }

  // epilogue: D col = lane&15 (n), row = quad*4 + reg (m)  [m89-verified]
#pragma unroll
  for (int i = 0; i < 4; ++i) {
    const int mloc = wm * 64 + i * 16 + quad * 4;
#pragma unroll
    for (int j = 0; j < 4; ++j) {
      const int np = n0 + wn * 64 + j * 16 + ln;
      if (EPI == 0 || EPI == 1) {
        ushort4 pk;
        unsigned short* pp = (unsigned short*)&pk;
#pragma unroll
        for (int r = 0; r < 4; ++r) {
          float v = aS[mloc + r] * acc[i][j][r] + bS[mloc + r];
          v = (EPI == 0) ? tanhf(v) : fmaxf(v, 0.f);
          pp[r] = bf16r(v);
        }
        *(ushort4*)((unsigned short*)outp + (size_t)np * M + m0 + mloc) = pk;
      } else {
        int b = np / HW_, hw = np - b * HW_;
        size_t base = ((size_t)b * C_ + m0 + mloc) * HW_ + hw;
#pragma unroll
        for (int r = 0; r < 4; ++r) {
          size_t o = base + (size_t)r * HW_;
          ((float*)outp)[o] =
              aS[mloc + r] * acc[i][j][r] + bS[mloc + r] + xskip[o];
        }
      }
    }
  }
}

// ---------------------------------------------------------------------------
// x (planar fp32) -> x_T (bf16, [b*HW+px][c])  via LDS transpose.
// ---------------------------------------------------------------------------
__global__ __launch_bounds__(256)
void transpose_x(const float* __restrict__ x, unsigned short* __restrict__ xT) {
  __shared__ unsigned short tile[128 * 72];
  const int tid = threadIdx.x;
  const int px0 = blockIdx.x * 128;
  for (int p = 0; p < 4; ++p) {
    if (p) __syncthreads();
#pragma unroll
    for (int e = 0; e < 32; ++e) {
      int flat = e * 256 + tid;
      int cl = flat >> 7, pxl = flat & 127;
      int px = px0 + pxl;
      int b = px / HW_, hw = px - b * HW_;
      tile[pxl * 72 + cl] = bf16r(x[((size_t)b * C_ + p * 64 + cl) * HW_ + hw]);
    }
    __syncthreads();
    int px = tid >> 1, half = tid & 1;
    const unsigned short* src = &tile[px * 72 + half * 32];
    unsigned short* dst = &xT[(size_t)(px0 + px) * C_ + p * 64 + half * 32];
    *(uint4*)(dst + 0) = *(const uint4*)(src + 0);
    *(uint4*)(dst + 8) = *(const uint4*)(src + 8);
    *(uint4*)(dst + 16) = *(const uint4*)(src + 16);
    *(uint4*)(dst + 24) = *(const uint4*)(src + 24);
  }
}

// weights fp32 -> bf16 (all four mats)
__global__ __launch_bounds__(256)
void wconv(const float* __restrict__ w1, const float* __restrict__ rw,
           const float* __restrict__ sw, const float* __restrict__ w3,
           unsigned short* __restrict__ o1, unsigned short* __restrict__ orw,
           unsigned short* __restrict__ osw, unsigned short* __restrict__ ow3) {
  int i = blockIdx.x * 256 + threadIdx.x;
  if (i < 65536) o1[i] = bf16r(w1[i]);
  if (i < 16384) orw[i] = bf16r(rw[i]);
  if (i < 50176) osw[i] = bf16r(sw[i]);
  if (i < 65536) ow3[i] = bf16r(w3[i]);
}

// ---------------------------------------------------------------------------
// Gather v6: phase-3 remapped to wave=gc-quad / lane=strip so the per-pixel
// weights (shared by all 16 gc) are loaded+converted ONCE per 4 gc instead of
// once per gc.  Per 16 outputs: 784 FMA + 196 cvt + 133 LDS reads (was
// 784+784+280).  tb bounce flips to [gc][px+pad] so the new writer's ushort4
// stores stay bank-spread.  Grid order swapped to g-fastest so the 16 blocks
// sharing one rT stripe land adjacently -> L2 reuse (rT HBM ~16x -> ~8x).
// LDS: patch 41216 + union(rs+sws 36864 | wts 22736 + tb2 7296) + params
//      = ~78.4 KB -> 2 blocks/CU (unchanged).
// ---------------------------------------------------------------------------
constexpr int P_GC_STR = 644;   // fp32 plane: 10r*64c + 4 pad
constexpr int W_TAP_STR = 232;  // ushort: 224 px + 8 pad
constexpr int TB_STR = 228;     // ushort: 224 px + 4 pad (tb2 [gc][px])

__global__ __launch_bounds__(256)
void gather_inv(const unsigned short* __restrict__ yT,
                const unsigned short* __restrict__ rT,
                const unsigned short* __restrict__ spanw,  // [784][64] bf16
                const float* __restrict__ spanb,           // [784] fp32
                const float* __restrict__ g2, const float* __restrict__ b2,
                const float* __restrict__ m2, const float* __restrict__ v2,
                unsigned short* __restrict__ tT) {
  __shared__ float patch[16 * P_GC_STR];            // 41216 B
  __shared__ __align__(16) unsigned short reg2[18432];  // 36864 B union
  __shared__ float a2s[16], b2s[16], sbs[KK_];

  unsigned short* rs = reg2;           // 224*64 shorts (swizzled rows)
  unsigned short* sws = reg2 + 14336;  // 64*64 shorts (swizzled rows)
  unsigned short* wts = reg2;                    // aliases after phase 1
  unsigned short* tb2 = reg2 + KK_ * W_TAP_STR;  // [16][TB_STR] shorts

  const int tid = threadIdx.x;
  const int g = blockIdx.x;   // g fastest: 16 blocks sharing rT stripe adjacent
  const int st = blockIdx.y;  // 4-row stripe 0..13
  const int b = blockIdx.z;
  const int h0 = st * 4;
  const int wave = tid >> 6, lane = tid & 63;
  const int lq = lane & 7, lr8 = lane >> 3;
  const int quad = lane >> 4, ln = lane & 15;

  // ---- phase 0: staging ----
  {
    // rs: 224 rows (stripe pixels) x 64k bf16, XOR-swizzled chunks
    const unsigned short* rbase = rT + ((size_t)b * HW_ + h0 * W_) * RED_;
#pragma unroll
    for (int t = 0; t < 7; ++t) {
      int inst = wave * 7 + t;
      int row = inst * 8 + lr8;
      int qs = lq ^ (row & 7);
      gl_lds16(rbase + (size_t)row * RED_ + qs * 8, &rs[inst * 512]);
    }
    // sws: 64 rows (taps, clamped at 48) x 64k
    const unsigned short* swg = spanw + (size_t)(g * KK_) * RED_;
#pragma unroll
    for (int t = 0; t < 2; ++t) {
      int inst = wave * 2 + t;
      int row = inst * 8 + lr8;
      int tap = min(row, KK_ - 1);
      int qs = lq ^ (row & 7);
      gl_lds16(swg + (size_t)tap * RED_ + qs * 8, &sws[inst * 512]);
    }
    if (tid < 16) {
      int c = g * GC_ + tid;
      float sc = g2[c] * rsqrtf(v2[c] + DEV_EPS);
      a2s[tid] = sc;
      b2s[tid] = b2[c] - m2[c] * sc;
    }
    if (tid < KK_) sbs[tid] = spanb[g * KK_ + tid];
    // patch: 620 positions (10r x 62c), all 16 gc per position from y_T
    for (int e = tid; e < 620; e += 256) {
      int row = e / 62, cw = e - row * 62;
      int sr = h0 + row - 3, sc = cw - 3;
      int off = row * 64 + cw;
      if (sr >= 0 && sr < H_ && sc >= 0 && sc < W_) {
        const unsigned short* yp =
            yT + ((size_t)b * HW_ + sr * W_ + sc) * C_ + g * GC_;
        uint4 v0 = *(const uint4*)yp;
        uint4 v1 = *(const uint4*)(yp + 8);
        unsigned wv[8] = {v0.x, v0.y, v0.z, v0.w, v1.x, v1.y, v1.z, v1.w};
#pragma unroll
        for (int cc = 0; cc < 8; ++cc) {
          patch[(2 * cc) * P_GC_STR + off] = __uint_as_float(wv[cc] << 16);
          patch[(2 * cc + 1) * P_GC_STR + off] =
              __uint_as_float(wv[cc] & 0xffff0000u);
        }
      } else {
#pragma unroll
        for (int cc = 0; cc < 16; ++cc) patch[cc * P_GC_STR + off] = 0.f;
      }
    }
  }
  __syncthreads();  // drains vmcnt (global_load_lds) + patch writes

  // ---- phase 1: mini-MFMA  (wave = tap-tile) ----
  f32x4 wacc[14];
#pragma unroll
  for (int j = 0; j < 14; ++j)
#pragma unroll
    for (int e = 0; e < 4; ++e) wacc[j][e] = 0.f;
  {
    short8 af[2];
#pragma unroll
    for (int s = 0; s < 2; ++s) {
      int c = s * 4 + quad;
      int r = wave * 16 + ln;
      af[s] = *(const short8*)&sws[r * 64 + (c ^ (r & 7)) * 8];
    }
#pragma unroll
    for (int j = 0; j < 14; ++j) {
#pragma unroll
      for (int s = 0; s < 2; ++s) {
        int c = s * 4 + quad;
        int r = j * 16 + ln;
        short8 bf = *(const short8*)&rs[r * 64 + (c ^ (r & 7)) * 8];
        wacc[j] = __builtin_amdgcn_mfma_f32_16x16x32_bf16(af[s], bf, wacc[j],
                                                          0, 0, 0);
      }
    }
  }
  __syncthreads();  // all frag reads done; rs/sws region now dead

  // ---- phase 2: write wts[tap][px] bf16 (D: col=ln -> px, row=quad*4+r) ----
  {
#pragma unroll
    for (int r = 0; r < 4; ++r) {
      int tap = wave * 16 + quad * 4 + r;
      if (tap < KK_) {
        float sb = sbs[tap];
#pragma unroll
        for (int j = 0; j < 14; ++j)
          wts[tap * W_TAP_STR + j * 16 + ln] = bf16r(wacc[j][r] + sb);
      }
    }
  }
  __syncthreads();

  // ---- phase 3: 7x7 gather; wave = gc-quad q, lane = strip s (4 px) ----
  // weights shared across gc: convert once per di-row, reuse for 4 gc.
  {
    const int q = wave;        // handles gc = 4q .. 4q+3
    const int s = lane;        // strip id 0..55 (lanes 56-63 idle)
    if (s < 56) {
      const int r0 = s / 14, c0 = (s - r0 * 14) * 4;
      const int pxb = 4 * s;   // == r0*56 + c0
      float acc[4][4];
#pragma unroll
      for (int cc = 0; cc < 4; ++cc)
#pragma unroll
        for (int p = 0; p < 4; ++p) acc[cc][p] = 0.f;
      const unsigned short* wp = wts + pxb;
      const float* pbase = patch + r0 * 64 + c0;
#pragma unroll
      for (int di = 0; di < 7; ++di) {
        float wf[7][4];
#pragma unroll
        for (int dj = 0; dj < 7; ++dj) {
          ushort4 wv = *(const ushort4*)(wp + (di * 7 + dj) * W_TAP_STR);
          wf[dj][0] = bf2f(wv.x);
          wf[dj][1] = bf2f(wv.y);
          wf[dj][2] = bf2f(wv.z);
          wf[dj][3] = bf2f(wv.w);
        }
#pragma unroll
        for (int cc = 0; cc < 4; ++cc) {
          const float* pr = pbase + (4 * q + cc) * P_GC_STR + di * 64;
          float4 pa = *(const float4*)pr;
          float4 pb = *(const float4*)(pr + 4);
          float4 pc2 = *(const float4*)(pr + 8);
          float pf[12] = {pa.x, pa.y, pa.z, pa.w, pb.x, pb.y,
                          pb.z, pb.w, pc2.x, pc2.y, pc2.z, pc2.w};
#pragma unroll
          for (int dj = 0; dj < 7; ++dj) {
#pragma unroll
            for (int p = 0; p < 4; ++p)
              acc[cc][p] += wf[dj][p] * pf[dj + p];
          }
        }
      }
      // bn2 + tanh -> tb2[gc][px] (ushort4 per gc, bank-spread over s)
#pragma unroll
      for (int cc = 0; cc < 4; ++cc) {
        const int gc = 4 * q + cc;
        const float al = a2s[gc], be = b2s[gc];
        ushort4 o;
        o.x = bf16r(tanhf(al * acc[cc][0] + be));
        o.y = bf16r(tanhf(al * acc[cc][1] + be));
        o.z = bf16r(tanhf(al * acc[cc][2] + be));
        o.w = bf16r(tanhf(al * acc[cc][3] + be));
        *(ushort4*)&tb2[gc * TB_STR + pxb] = o;
      }
    }
  }
  __syncthreads();

  if (tid < 224) {
    alignas(16) unsigned short v[16];
#pragma unroll
    for (int gc = 0; gc < 16; ++gc) v[gc] = tb2[gc * TB_STR + tid];
    unsigned short* dst = tT + ((size_t)b * HW_ + h0 * W_ + tid) * C_ + g * GC_;
    *(uint4*)(dst + 0) = *(const uint4*)&v[0];
    *(uint4*)(dst + 8) = *(const uint4*)&v[8];
  }
}

}  // namespace

extern "C" void kernel_launch(void* const* d_in, const int* in_sizes, int n_in,
                              void* d_out, int out_size, void* d_ws, size_t ws_size,
                              hipStream_t stream) {
  const float* x = (const float*)d_in[0];
  const float* w1 = (const float*)d_in[1];
  const float* b1 = (const float*)d_in[2];
  const float* bn1g = (const float*)d_in[3];
  const float* bn1b = (const float*)d_in[4];
  const float* bn1m = (const float*)d_in[5];
  const float* bn1v = (const float*)d_in[6];
  const float* red_w = (const float*)d_in[7];
  const float* red_b = (const float*)d_in[8];
  const float* rbg = (const float*)d_in[9];
  const float* rbb = (const float*)d_in[10];
  const float* rbm = (const float*)d_in[11];
  const float* rbv = (const float*)d_in[12];
  const float* span_w = (const float*)d_in[13];
  const float* span_b = (const float*)d_in[14];
  const float* bn2g = (const float*)d_in[15];
  const float* bn2b = (const float*)d_in[16];
  const float* bn2m = (const float*)d_in[17];
  const float* bn2v = (const float*)d_in[18];
  const float* w3 = (const float*)d_in[19];
  const float* b3 = (const float*)d_in[20];
  const float* bn3g = (const float*)d_in[21];
  const float* bn3b = (const float*)d_in[22];
  const float* bn3m = (const float*)d_in[23];
  const float* bn3v = (const float*)d_in[24];

  unsigned short* ws = (unsigned short*)d_ws;
  unsigned short* xT = ws;                       // 50176*256
  unsigned short* yT = xT + (size_t)NTOT * C_;   // 50176*256
  unsigned short* rT = yT + (size_t)NTOT * C_;   // 50176*64
  unsigned short* tT = rT + (size_t)NTOT * RED_; // 50176*256
  unsigned short* w1b = tT + (size_t)NTOT * C_;
  unsigned short* redb = w1b + 65536;
  unsigned short* spanb = redb + 16384;
  unsigned short* w3b = spanb + 50176;
  float* out = (float*)d_out;

  dim3 blk(256);
  wconv<<<dim3(256), blk, 0, stream>>>(w1, red_w, span_w, w3, w1b, redb, spanb, w3b);
  transpose_x<<<dim3(392), blk, 0, stream>>>(x, xT);
  // y_T = tanh(bn1(w1 @ x))
  mfma_gemm<2, 2, 256, 0><<<dim3(392, 2), blk, 0, stream>>>(
      w1b, xT, b1, bn1g, bn1b, bn1m, bn1v, nullptr, yT, C_);
  // r_T = relu(bn_red(red_w @ y))
  mfma_gemm<1, 4, 256, 1><<<dim3(196, 1), blk, 0, stream>>>(
      redb, yT, red_b, rbg, rbb, rbm, rbv, nullptr, rT, RED_);
  // t_T = tanh(bn2(involution(y; span(r))))  — span fused in, g-fastest grid
  gather_inv<<<dim3(16, 14, 16), blk, 0, stream>>>(
      yT, rT, spanb, span_b, bn2g, bn2b, bn2m, bn2v, tT);
  // out = bn3(w3 @ t) + x  (planar fp32)
  mfma_gemm<2, 2, 256, 3><<<dim3(392, 2), blk, 0, stream>>>(
      w3b, tT, b3, bn3g, bn3b, bn3m, bn3v, x, out, C_);
}

// Round 2
// 337.516 us; speedup vs baseline: 1.2236x; 1.2236x over previous
//
#include <hip/hip_runtime.h>
#include <math.h>

#define DEV_EPS 1e-5f

namespace {
constexpr int B_ = 16, C_ = 256, H_ = 56, W_ = 56, HW_ = H_ * W_;
constexpr int G_ = 16, GC_ = 16, RED_ = 64, KK_ = 49;
constexpr int NTOT = B_ * HW_;  // 50176 flattened (batch, pixel)

typedef __attribute__((ext_vector_type(8))) short short8;
typedef __attribute__((ext_vector_type(4))) float f32x4;

__device__ __forceinline__ unsigned short bf16r(float f) {
  unsigned u = __float_as_uint(f);
  u += 0x7fff + ((u >> 16) & 1);  // RNE
  return (unsigned short)(u >> 16);
}
__device__ __forceinline__ float bf2f(unsigned short s) {
  return __uint_as_float((unsigned)s << 16);
}

// tanh(x) = sign(x)*(1-e)/(1+e), e = exp(-2|x|).  ~8 VALU ops vs ~25 for
// OCML tanhf.  v_exp_f32 ~1ulp; error invisible under bf16 output rounding.
__device__ __forceinline__ float fast_tanh(float x) {
  float ax = fabsf(x);
  float e = __expf(-2.0f * ax);
  float r = (1.0f - e) * __builtin_amdgcn_rcpf(1.0f + e);
  return copysignf(r, x);
}

// async global->LDS, 16B per lane. LDS dest is wave-uniform base + lane*16
// (m104: no per-lane LDS scatter) — so any swizzle goes on the GLOBAL address.
__device__ __forceinline__ void gl_lds16(const void* g, void* l) {
  __builtin_amdgcn_global_load_lds(
      (const __attribute__((address_space(1))) unsigned int*)g,
      (__attribute__((address_space(3))) unsigned int*)l, 16, 0, 0);
}

// ---------------------------------------------------------------------------
// MFMA GEMM: D[m][n] = sum_k Wt[m][k] * Act[n][k]   (both bf16, k-contiguous)
// Block = 256 threads = 4 waves; wave tile 64x64; BM=WM*64, BN=WN*64, BK=64.
// LDS tiles [row][64k] bf16, 128B rows; global chunk q^(row&7) XOR-swizzle so
// frag ds_read_b128 is 2-way-only (free, m136).
// EPI: 0 = tanh(bn)->act_T bf16, 1 = relu(bn)->act_T bf16,
//      3 = bn + x skip -> planar fp32 [b][C][HW] (final out)
// ---------------------------------------------------------------------------
template <int WM, int WN, int KD, int EPI>
__global__ __launch_bounds__(256)
void mfma_gemm(const unsigned short* __restrict__ A,   // [M][KD] bf16
               const unsigned short* __restrict__ Act, // [NTOT][KD] bf16
               const float* __restrict__ p0,
               const float* __restrict__ bg, const float* __restrict__ bb,
               const float* __restrict__ bm, const float* __restrict__ bv,
               const float* __restrict__ xskip, void* __restrict__ outp,
               int M) {
  constexpr int BM = WM * 64, BN = WN * 64;
  __shared__ unsigned short At[BM * 64];
  __shared__ unsigned short Bt[BN * 64];
  __shared__ float aS[BM], bS[BM];

  const int tid = threadIdx.x;
  const int n0 = blockIdx.x * BN, m0 = blockIdx.y * BM;
  const int wave = tid >> 6, lane = tid & 63;
  const int wm = (WM == 2) ? (wave >> 1) : 0;
  const int wn = (WM == 2) ? (wave & 1) : wave;

  if (tid < BM) {
    int m = min(m0 + tid, M - 1);
    float sc = bg[m] * rsqrtf(bv[m] + DEV_EPS);
    aS[tid] = sc;
    bS[tid] = sc * p0[m] + bb[m] - bm[m] * sc;
  }

  f32x4 acc[4][4];
#pragma unroll
  for (int i = 0; i < 4; ++i)
#pragma unroll
    for (int j = 0; j < 4; ++j)
#pragma unroll
      for (int e = 0; e < 4; ++e) acc[i][j][e] = 0.f;

  const int lq = lane & 7;          // chunk slot within a row-octet
  const int lr8 = lane >> 3;        // row within octet group
  const int quad = lane >> 4, ln = lane & 15;

#pragma unroll 1
  for (int kt = 0; kt < KD / 64; ++kt) {
    __syncthreads();  // protect LDS from previous iteration's readers
    // stage A: BM rows x 64k; one instr = 8 rows (1KB)
#pragma unroll
    for (int t = 0; t < BM / 32; ++t) {
      int inst = wave * (BM / 32) + t;
      int row = inst * 8 + lr8;
      int mrow = min(m0 + row, M - 1);
      int qs = lq ^ (row & 7);
      gl_lds16(A + (size_t)mrow * KD + kt * 64 + qs * 8, &At[inst * 512]);
    }
    // stage B (activations)
#pragma unroll
    for (int t = 0; t < BN / 32; ++t) {
      int inst = wave * (BN / 32) + t;
      int row = inst * 8 + lr8;
      int qs = lq ^ (row & 7);
      gl_lds16(Act + (size_t)(n0 + row) * KD + kt * 64 + qs * 8, &Bt[inst * 512]);
    }
    __syncthreads();  // barrier drains vmcnt -> LDS tiles complete

#pragma unroll
    for (int s = 0; s < 2; ++s) {
      const int c = s * 4 + quad;
      short8 af[4], bf[4];
#pragma unroll
      for (int i = 0; i < 4; ++i) {
        int r = wm * 64 + i * 16 + ln;
        af[i] = *(const short8*)&At[r * 64 + (c ^ (r & 7)) * 8];
      }
#pragma unroll
      for (int j = 0; j < 4; ++j) {
        int r = wn * 64 + j * 16 + ln;
        bf[j] = *(const short8*)&Bt[r * 64 + (c ^ (r & 7)) * 8];
      }
#pragma unroll
      for (int i = 0; i < 4; ++i)
#pragma unroll
        for (int j = 0; j < 4; ++j)
          acc[i][j] = __builtin_amdgcn_mfma_f32_16x16x32_bf16(af[i], bf[j],
                                                              acc[i][j], 0, 0, 0);
    }
  }

  // epilogue: D col = lane&15 (n), row = quad*4 + reg (m)  [m89-verified]
#pragma unroll
  for (int i = 0; i < 4; ++i) {
    const int mloc = wm * 64 + i * 16 + quad * 4;
#pragma unroll
    for (int j = 0; j < 4; ++j) {
      const int np = n0 + wn * 64 + j * 16 + ln;
      if (EPI == 0 || EPI == 1) {
        ushort4 pk;
        unsigned short* pp = (unsigned short*)&pk;
#pragma unroll
        for (int r = 0; r < 4; ++r) {
          float v = aS[mloc + r] * acc[i][j][r] + bS[mloc + r];
          v = (EPI == 0) ? fast_tanh(v) : fmaxf(v, 0.f);
          pp[r] = bf16r(v);
        }
        *(ushort4*)((unsigned short*)outp + (size_t)np * M + m0 + mloc) = pk;
      } else {
        int b = np / HW_, hw = np - b * HW_;
        size_t base = ((size_t)b * C_ + m0 + mloc) * HW_ + hw;
#pragma unroll
        for (int r = 0; r < 4; ++r) {
          size_t o = base + (size_t)r * HW_;
          ((float*)outp)[o] =
              aS[mloc + r] * acc[i][j][r] + bS[mloc + r] + xskip[o];
        }
      }
    }
  }
}

// ---------------------------------------------------------------------------
// x (planar fp32) -> x_T (bf16, [b*HW+px][c])  via LDS transpose.
// ---------------------------------------------------------------------------
__global__ __launch_bounds__(256)
void transpose_x(const float* __restrict__ x, unsigned short* __restrict__ xT) {
  __shared__ unsigned short tile[128 * 72];
  const int tid = threadIdx.x;
  const int px0 = blockIdx.x * 128;
  for (int p = 0; p < 4; ++p) {
    if (p) __syncthreads();
#pragma unroll
    for (int e = 0; e < 32; ++e) {
      int flat = e * 256 + tid;
      int cl = flat >> 7, pxl = flat & 127;
      int px = px0 + pxl;
      int b = px / HW_, hw = px - b * HW_;
      tile[pxl * 72 + cl] = bf16r(x[((size_t)b * C_ + p * 64 + cl) * HW_ + hw]);
    }
    __syncthreads();
    int px = tid >> 1, half = tid & 1;
    const unsigned short* src = &tile[px * 72 + half * 32];
    unsigned short* dst = &xT[(size_t)(px0 + px) * C_ + p * 64 + half * 32];
    *(uint4*)(dst + 0) = *(const uint4*)(src + 0);
    *(uint4*)(dst + 8) = *(const uint4*)(src + 8);
    *(uint4*)(dst + 16) = *(const uint4*)(src + 16);
    *(uint4*)(dst + 24) = *(const uint4*)(src + 24);
  }
}

// weights fp32 -> bf16 (all four mats)
__global__ __launch_bounds__(256)
void wconv(const float* __restrict__ w1, const float* __restrict__ rw,
           const float* __restrict__ sw, const float* __restrict__ w3,
           unsigned short* __restrict__ o1, unsigned short* __restrict__ orw,
           unsigned short* __restrict__ osw, unsigned short* __restrict__ ow3) {
  int i = blockIdx.x * 256 + threadIdx.x;
  if (i < 65536) o1[i] = bf16r(w1[i]);
  if (i < 16384) orw[i] = bf16r(rw[i]);
  if (i < 50176) osw[i] = bf16r(sw[i]);
  if (i < 65536) ow3[i] = bf16r(w3[i]);
}

// ---------------------------------------------------------------------------
// Gather v7: phase 3 reverted to v5's proven mapping (item = (strip, gc);
// v6's gc-inner remap blew VGPR 116->244, halved occupancy, +50us).
// KEPT from v6: g-fastest grid (FETCH 113->75 MB, L2 reuse of rT + yT lines
// across the 16 g-blocks of one (b,st)).  NEW: fast_tanh (~8 ops vs ~25).
// LDS: patch 41216 + union(rs+sws 36864 | wts 22736 + tb 7168) + params
//      = ~78.4 KB -> 2 blocks/CU.
// ---------------------------------------------------------------------------
constexpr int P_GC_STR = 644;   // fp32 plane: 10r*64c + 4 pad
constexpr int W_TAP_STR = 232;  // ushort: 224 px + 8 pad

__global__ __launch_bounds__(256)
void gather_inv(const unsigned short* __restrict__ yT,
                const unsigned short* __restrict__ rT,
                const unsigned short* __restrict__ spanw,  // [784][64] bf16
                const float* __restrict__ spanb,           // [784] fp32
                const float* __restrict__ g2, const float* __restrict__ b2,
                const float* __restrict__ m2, const float* __restrict__ v2,
                unsigned short* __restrict__ tT) {
  __shared__ float patch[16 * P_GC_STR];            // 41216 B
  __shared__ __align__(16) unsigned short reg2[18432];  // 36864 B union
  __shared__ float a2s[16], b2s[16], sbs[KK_];

  unsigned short* rs = reg2;           // 224*64 shorts (swizzled rows)
  unsigned short* sws = reg2 + 14336;  // 64*64 shorts (swizzled rows)
  unsigned short* wts = reg2;                    // aliases after phase 1
  unsigned short* tb = reg2 + KK_ * W_TAP_STR;   // 224*16 shorts

  const int tid = threadIdx.x;
  const int g = blockIdx.x;   // g fastest: 16 blocks sharing rT stripe adjacent
  const int st = blockIdx.y;  // 4-row stripe 0..13
  const int b = blockIdx.z;
  const int h0 = st * 4;
  const int wave = tid >> 6, lane = tid & 63;
  const int lq = lane & 7, lr8 = lane >> 3;
  const int quad = lane >> 4, ln = lane & 15;

  // ---- phase 0: staging ----
  {
    // rs: 224 rows (stripe pixels) x 64k bf16, XOR-swizzled chunks
    const unsigned short* rbase = rT + ((size_t)b * HW_ + h0 * W_) * RED_;
#pragma unroll
    for (int t = 0; t < 7; ++t) {
      int inst = wave * 7 + t;
      int row = inst * 8 + lr8;
      int qs = lq ^ (row & 7);
      gl_lds16(rbase + (size_t)row * RED_ + qs * 8, &rs[inst * 512]);
    }
    // sws: 64 rows (taps, clamped at 48) x 64k
    const unsigned short* swg = spanw + (size_t)(g * KK_) * RED_;
#pragma unroll
    for (int t = 0; t < 2; ++t) {
      int inst = wave * 2 + t;
      int row = inst * 8 + lr8;
      int tap = min(row, KK_ - 1);
      int qs = lq ^ (row & 7);
      gl_lds16(swg + (size_t)tap * RED_ + qs * 8, &sws[inst * 512]);
    }
    if (tid < 16) {
      int c = g * GC_ + tid;
      float sc = g2[c] * rsqrtf(v2[c] + DEV_EPS);
      a2s[tid] = sc;
      b2s[tid] = b2[c] - m2[c] * sc;
    }
    if (tid < KK_) sbs[tid] = spanb[g * KK_ + tid];
    // patch: 620 positions (10r x 62c), all 16 gc per position from y_T
    for (int e = tid; e < 620; e += 256) {
      int row = e / 62, cw = e - row * 62;
      int sr = h0 + row - 3, sc = cw - 3;
      int off = row * 64 + cw;
      if (sr >= 0 && sr < H_ && sc >= 0 && sc < W_) {
        const unsigned short* yp =
            yT + ((size_t)b * HW_ + sr * W_ + sc) * C_ + g * GC_;
        uint4 v0 = *(const uint4*)yp;
        uint4 v1 = *(const uint4*)(yp + 8);
        unsigned wv[8] = {v0.x, v0.y, v0.z, v0.w, v1.x, v1.y, v1.z, v1.w};
#pragma unroll
        for (int cc = 0; cc < 8; ++cc) {
          patch[(2 * cc) * P_GC_STR + off] = __uint_as_float(wv[cc] << 16);
          patch[(2 * cc + 1) * P_GC_STR + off] =
              __uint_as_float(wv[cc] & 0xffff0000u);
        }
      } else {
#pragma unroll
        for (int cc = 0; cc < 16; ++cc) patch[cc * P_GC_STR + off] = 0.f;
      }
    }
  }
  __syncthreads();  // drains vmcnt (global_load_lds) + patch writes

  // ---- phase 1: mini-MFMA  (wave = tap-tile) ----
  f32x4 wacc[14];
#pragma unroll
  for (int j = 0; j < 14; ++j)
#pragma unroll
    for (int e = 0; e < 4; ++e) wacc[j][e] = 0.f;
  {
    short8 af[2];
#pragma unroll
    for (int s = 0; s < 2; ++s) {
      int c = s * 4 + quad;
      int r = wave * 16 + ln;
      af[s] = *(const short8*)&sws[r * 64 + (c ^ (r & 7)) * 8];
    }
#pragma unroll
    for (int j = 0; j < 14; ++j) {
#pragma unroll
      for (int s = 0; s < 2; ++s) {
        int c = s * 4 + quad;
        int r = j * 16 + ln;
        short8 bf = *(const short8*)&rs[r * 64 + (c ^ (r & 7)) * 8];
        wacc[j] = __builtin_amdgcn_mfma_f32_16x16x32_bf16(af[s], bf, wacc[j],
                                                          0, 0, 0);
      }
    }
  }
  __syncthreads();  // all frag reads done; rs/sws region now dead

  // ---- phase 2: write wts[tap][px] bf16 (D: col=ln -> px, row=quad*4+r) ----
  {
#pragma unroll
    for (int r = 0; r < 4; ++r) {
      int tap = wave * 16 + quad * 4 + r;
      if (tap < KK_) {
        float sb = sbs[tap];
#pragma unroll
        for (int j = 0; j < 14; ++j)
          wts[tap * W_TAP_STR + j * 16 + ln] = bf16r(wacc[j][r] + sb);
      }
    }
  }
  __syncthreads();

  // ---- phase 3: 7x7 gather; item = (px4 strip s, gc) ----
#pragma unroll 1
  for (int it = 0; it < 4; ++it) {
    int item = tid + it * 256;
    if (item < 56 * 16) {
      const int gc = item & 15, s = item >> 4;
      const int r0 = s / 14, c0 = (s - r0 * 14) * 4;
      const float* prow0 = patch + gc * P_GC_STR + r0 * 64 + c0;
      const unsigned short* wp = wts + (r0 * 56 + c0);
      float acc0 = 0.f, acc1 = 0.f, acc2 = 0.f, acc3 = 0.f;
#pragma unroll
      for (int di = 0; di < 7; ++di) {
        const float* pr = prow0 + di * 64;
        float4 pa = *(const float4*)pr;
        float4 pb = *(const float4*)(pr + 4);
        float4 pc2 = *(const float4*)(pr + 8);
        float pf[12] = {pa.x, pa.y, pa.z, pa.w, pb.x, pb.y,
                        pb.z, pb.w, pc2.x, pc2.y, pc2.z, pc2.w};
#pragma unroll
        for (int dj = 0; dj < 7; ++dj) {
          ushort4 wv = *(const ushort4*)(wp + (di * 7 + dj) * W_TAP_STR);
          acc0 += bf2f(wv.x) * pf[dj + 0];
          acc1 += bf2f(wv.y) * pf[dj + 1];
          acc2 += bf2f(wv.z) * pf[dj + 2];
          acc3 += bf2f(wv.w) * pf[dj + 3];
        }
      }
      const float al = a2s[gc], be = b2s[gc];
      const int pxb = r0 * 56 + c0;
      tb[(pxb + 0) * 16 + gc] = bf16r(fast_tanh(al * acc0 + be));
      tb[(pxb + 1) * 16 + gc] = bf16r(fast_tanh(al * acc1 + be));
      tb[(pxb + 2) * 16 + gc] = bf16r(fast_tanh(al * acc2 + be));
      tb[(pxb + 3) * 16 + gc] = bf16r(fast_tanh(al * acc3 + be));
    }
  }
  __syncthreads();

  if (tid < 224) {
    unsigned short* dst = tT + ((size_t)b * HW_ + h0 * W_ + tid) * C_ + g * GC_;
    *(uint4*)(dst + 0) = *(const uint4*)&tb[tid * 16];
    *(uint4*)(dst + 8) = *(const uint4*)&tb[tid * 16 + 8];
  }
}

}  // namespace

extern "C" void kernel_launch(void* const* d_in, const int* in_sizes, int n_in,
                              void* d_out, int out_size, void* d_ws, size_t ws_size,
                              hipStream_t stream) {
  const float* x = (const float*)d_in[0];
  const float* w1 = (const float*)d_in[1];
  const float* b1 = (const float*)d_in[2];
  const float* bn1g = (const float*)d_in[3];
  const float* bn1b = (const float*)d_in[4];
  const float* bn1m = (const float*)d_in[5];
  const float* bn1v = (const float*)d_in[6];
  const float* red_w = (const float*)d_in[7];
  const float* red_b = (const float*)d_in[8];
  const float* rbg = (const float*)d_in[9];
  const float* rbb = (const float*)d_in[10];
  const float* rbm = (const float*)d_in[11];
  const float* rbv = (const float*)d_in[12];
  const float* span_w = (const float*)d_in[13];
  const float* span_b = (const float*)d_in[14];
  const float* bn2g = (const float*)d_in[15];
  const float* bn2b = (const float*)d_in[16];
  const float* bn2m = (const float*)d_in[17];
  const float* bn2v = (const float*)d_in[18];
  const float* w3 = (const float*)d_in[19];
  const float* b3 = (const float*)d_in[20];
  const float* bn3g = (const float*)d_in[21];
  const float* bn3b = (const float*)d_in[22];
  const float* bn3m = (const float*)d_in[23];
  const float* bn3v = (const float*)d_in[24];

  unsigned short* ws = (unsigned short*)d_ws;
  unsigned short* xT = ws;                       // 50176*256
  unsigned short* yT = xT + (size_t)NTOT * C_;   // 50176*256
  unsigned short* rT = yT + (size_t)NTOT * C_;   // 50176*64
  unsigned short* tT = rT + (size_t)NTOT * RED_; // 50176*256
  unsigned short* w1b = tT + (size_t)NTOT * C_;
  unsigned short* redb = w1b + 65536;
  unsigned short* spanb = redb + 16384;
  unsigned short* w3b = spanb + 50176;
  float* out = (float*)d_out;

  dim3 blk(256);
  wconv<<<dim3(256), blk, 0, stream>>>(w1, red_w, span_w, w3, w1b, redb, spanb, w3b);
  transpose_x<<<dim3(392), blk, 0, stream>>>(x, xT);
  // y_T = tanh(bn1(w1 @ x))
  mfma_gemm<2, 2, 256, 0><<<dim3(392, 2), blk, 0, stream>>>(
      w1b, xT, b1, bn1g, bn1b, bn1m, bn1v, nullptr, yT, C_);
  // r_T = relu(bn_red(red_w @ y))
  mfma_gemm<1, 4, 256, 1><<<dim3(196, 1), blk, 0, stream>>>(
      redb, yT, red_b, rbg, rbb, rbm, rbv, nullptr, rT, RED_);
  // t_T = tanh(bn2(involution(y; span(r))))  — span fused in, g-fastest grid
  gather_inv<<<dim3(16, 14, 16), blk, 0, stream>>>(
      yT, rT, spanb, span_b, bn2g, bn2b, bn2m, bn2v, tT);
  // out = bn3(w3 @ t) + x  (planar fp32)
  mfma_gemm<2, 2, 256, 3><<<dim3(392, 2), blk, 0, stream>>>(
      w3b, tT, b3, bn3g, bn3b, bn3m, bn3v, x, out, C_);
}

// Round 3
// 321.460 us; speedup vs baseline: 1.2847x; 1.0499x over previous
//
#include <hip/hip_runtime.h>
#include <math.h>

#define DEV_EPS 1e-5f

namespace {
constexpr int B_ = 16, C_ = 256, H_ = 56, W_ = 56, HW_ = H_ * W_;
constexpr int G_ = 16, GC_ = 16, RED_ = 64, KK_ = 49;
constexpr int NTOT = B_ * HW_;  // 50176 flattened (batch, pixel)

typedef __attribute__((ext_vector_type(8))) short short8;
typedef __attribute__((ext_vector_type(4))) float f32x4;

__device__ __forceinline__ unsigned short bf16r(float f) {
  unsigned u = __float_as_uint(f);
  u += 0x7fff + ((u >> 16) & 1);  // RNE
  return (unsigned short)(u >> 16);
}
__device__ __forceinline__ float bf2f(unsigned short s) {
  return __uint_as_float((unsigned)s << 16);
}

// tanh(x) = sign(x)*(1-e)/(1+e), e = exp(-2|x|).  ~8 VALU ops vs ~25 for
// OCML tanhf.  v_exp_f32 ~1ulp; error invisible under bf16 output rounding.
__device__ __forceinline__ float fast_tanh(float x) {
  float ax = fabsf(x);
  float e = __expf(-2.0f * ax);
  float r = (1.0f - e) * __builtin_amdgcn_rcpf(1.0f + e);
  return copysignf(r, x);
}

// async global->LDS, 16B per lane. LDS dest is wave-uniform base + lane*16
// (m104: no per-lane LDS scatter) — so any swizzle goes on the GLOBAL address.
__device__ __forceinline__ void gl_lds16(const void* g, void* l) {
  __builtin_amdgcn_global_load_lds(
      (const __attribute__((address_space(1))) unsigned int*)g,
      (__attribute__((address_space(3))) unsigned int*)l, 16, 0, 0);
}

// ---------------------------------------------------------------------------
// MFMA GEMM: D[m][n] = sum_k Wt[m][k] * Act[n][k]   (both bf16, k-contiguous)
// Block = 256 threads = 4 waves; wave tile 64x64; BM=WM*64, BN=WN*64, BK=64.
// LDS tiles [row][64k] bf16, 128B rows; global chunk q^(row&7) XOR-swizzle so
// frag ds_read_b128 is 2-way-only (free, m136).
// EPI: 0 = tanh(bn)->act_T bf16, 1 = relu(bn)->act_T bf16,
//      3 = bn + x skip -> planar fp32 [b][C][HW] (final out)
// ---------------------------------------------------------------------------
template <int WM, int WN, int KD, int EPI>
__global__ __launch_bounds__(256)
void mfma_gemm(const unsigned short* __restrict__ A,   // [M][KD] bf16
               const unsigned short* __restrict__ Act, // [NTOT][KD] bf16
               const float* __restrict__ p0,
               const float* __restrict__ bg, const float* __restrict__ bb,
               const float* __restrict__ bm, const float* __restrict__ bv,
               const float* __restrict__ xskip, void* __restrict__ outp,
               int M) {
  constexpr int BM = WM * 64, BN = WN * 64;
  __shared__ unsigned short At[BM * 64];
  __shared__ unsigned short Bt[BN * 64];
  __shared__ float aS[BM], bS[BM];

  const int tid = threadIdx.x;
  const int n0 = blockIdx.x * BN, m0 = blockIdx.y * BM;
  const int wave = tid >> 6, lane = tid & 63;
  const int wm = (WM == 2) ? (wave >> 1) : 0;
  const int wn = (WM == 2) ? (wave & 1) : wave;

  if (tid < BM) {
    int m = min(m0 + tid, M - 1);
    float sc = bg[m] * rsqrtf(bv[m] + DEV_EPS);
    aS[tid] = sc;
    bS[tid] = sc * p0[m] + bb[m] - bm[m] * sc;
  }

  f32x4 acc[4][4];
#pragma unroll
  for (int i = 0; i < 4; ++i)
#pragma unroll
    for (int j = 0; j < 4; ++j)
#pragma unroll
      for (int e = 0; e < 4; ++e) acc[i][j][e] = 0.f;

  const int lq = lane & 7;          // chunk slot within a row-octet
  const int lr8 = lane >> 3;        // row within octet group
  const int quad = lane >> 4, ln = lane & 15;

#pragma unroll 1
  for (int kt = 0; kt < KD / 64; ++kt) {
    __syncthreads();  // protect LDS from previous iteration's readers
    // stage A: BM rows x 64k; one instr = 8 rows (1KB)
#pragma unroll
    for (int t = 0; t < BM / 32; ++t) {
      int inst = wave * (BM / 32) + t;
      int row = inst * 8 + lr8;
      int mrow = min(m0 + row, M - 1);
      int qs = lq ^ (row & 7);
      gl_lds16(A + (size_t)mrow * KD + kt * 64 + qs * 8, &At[inst * 512]);
    }
    // stage B (activations)
#pragma unroll
    for (int t = 0; t < BN / 32; ++t) {
      int inst = wave * (BN / 32) + t;
      int row = inst * 8 + lr8;
      int qs = lq ^ (row & 7);
      gl_lds16(Act + (size_t)(n0 + row) * KD + kt * 64 + qs * 8, &Bt[inst * 512]);
    }
    __syncthreads();  // barrier drains vmcnt -> LDS tiles complete

#pragma unroll
    for (int s = 0; s < 2; ++s) {
      const int c = s * 4 + quad;
      short8 af[4], bf[4];
#pragma unroll
      for (int i = 0; i < 4; ++i) {
        int r = wm * 64 + i * 16 + ln;
        af[i] = *(const short8*)&At[r * 64 + (c ^ (r & 7)) * 8];
      }
#pragma unroll
      for (int j = 0; j < 4; ++j) {
        int r = wn * 64 + j * 16 + ln;
        bf[j] = *(const short8*)&Bt[r * 64 + (c ^ (r & 7)) * 8];
      }
#pragma unroll
      for (int i = 0; i < 4; ++i)
#pragma unroll
        for (int j = 0; j < 4; ++j)
          acc[i][j] = __builtin_amdgcn_mfma_f32_16x16x32_bf16(af[i], bf[j],
                                                              acc[i][j], 0, 0, 0);
    }
  }

  // epilogue: D col = lane&15 (n), row = quad*4 + reg (m)  [m89-verified]
#pragma unroll
  for (int i = 0; i < 4; ++i) {
    const int mloc = wm * 64 + i * 16 + quad * 4;
#pragma unroll
    for (int j = 0; j < 4; ++j) {
      const int np = n0 + wn * 64 + j * 16 + ln;
      if (EPI == 0 || EPI == 1) {
        ushort4 pk;
        unsigned short* pp = (unsigned short*)&pk;
#pragma unroll
        for (int r = 0; r < 4; ++r) {
          float v = aS[mloc + r] * acc[i][j][r] + bS[mloc + r];
          v = (EPI == 0) ? fast_tanh(v) : fmaxf(v, 0.f);
          pp[r] = bf16r(v);
        }
        *(ushort4*)((unsigned short*)outp + (size_t)np * M + m0 + mloc) = pk;
      } else {
        int b = np / HW_, hw = np - b * HW_;
        size_t base = ((size_t)b * C_ + m0 + mloc) * HW_ + hw;
#pragma unroll
        for (int r = 0; r < 4; ++r) {
          size_t o = base + (size_t)r * HW_;
          ((float*)outp)[o] =
              aS[mloc + r] * acc[i][j][r] + bS[mloc + r] + xskip[o];
        }
      }
    }
  }
}

// ---------------------------------------------------------------------------
// x (planar fp32) -> x_T (bf16, [b*HW+px][c])  via LDS transpose.
// ---------------------------------------------------------------------------
__global__ __launch_bounds__(256)
void transpose_x(const float* __restrict__ x, unsigned short* __restrict__ xT) {
  __shared__ unsigned short tile[128 * 72];
  const int tid = threadIdx.x;
  const int px0 = blockIdx.x * 128;
  for (int p = 0; p < 4; ++p) {
    if (p) __syncthreads();
#pragma unroll
    for (int e = 0; e < 32; ++e) {
      int flat = e * 256 + tid;
      int cl = flat >> 7, pxl = flat & 127;
      int px = px0 + pxl;
      int b = px / HW_, hw = px - b * HW_;
      tile[pxl * 72 + cl] = bf16r(x[((size_t)b * C_ + p * 64 + cl) * HW_ + hw]);
    }
    __syncthreads();
    int px = tid >> 1, half = tid & 1;
    const unsigned short* src = &tile[px * 72 + half * 32];
    unsigned short* dst = &xT[(size_t)(px0 + px) * C_ + p * 64 + half * 32];
    *(uint4*)(dst + 0) = *(const uint4*)(src + 0);
    *(uint4*)(dst + 8) = *(const uint4*)(src + 8);
    *(uint4*)(dst + 16) = *(const uint4*)(src + 16);
    *(uint4*)(dst + 24) = *(const uint4*)(src + 24);
  }
}

// weights fp32 -> bf16 (all four mats)
__global__ __launch_bounds__(256)
void wconv(const float* __restrict__ w1, const float* __restrict__ rw,
           const float* __restrict__ sw, const float* __restrict__ w3,
           unsigned short* __restrict__ o1, unsigned short* __restrict__ orw,
           unsigned short* __restrict__ osw, unsigned short* __restrict__ ow3) {
  int i = blockIdx.x * 256 + threadIdx.x;
  if (i < 65536) o1[i] = bf16r(w1[i]);
  if (i < 16384) orw[i] = bf16r(rw[i]);
  if (i < 50176) osw[i] = bf16r(sw[i]);
  if (i < 65536) ow3[i] = bf16r(w3[i]);
}

// ---------------------------------------------------------------------------
// Gather v8: LDS diet 78.8 -> ~51 KB => 3 blocks/CU (was 2).
//  * patch stored bf16 [16][648] (20.7 KB, was fp32 41.2 KB); phase 3 reads
//    3x ds_read_b64 + unpack per di-row (LDS cycles/item DROP; +84 VALU).
//  * single aliased blob: {rs 28.7K + sws 8.2K} (phases A/B) then
//    {patch 20.7K | wts 22.7K | tb 7K} (phases C/D) — rs/sws dead after MFMA.
//  * phase order: issue yT patch loads to regs (T14) -> stage rs/sws (async)
//    -> barrier -> mini-MFMA -> barrier -> write wts + patch -> barrier ->
//    gather -> barrier -> flush.
// Kept: g-fastest grid (FETCH 75 MB), fast_tanh, v5 phase-3 mapping.
// ---------------------------------------------------------------------------
constexpr int PB_STR = 648;     // ushort patch plane stride (640 used + 8 pad)
constexpr int W_TAP_STR = 232;  // ushort: 224 px + 8 pad
// blob layout (ushort offsets):
//  phase A/B: rs [0,14336), sws [14336,18432)
//  phase C/D: patch [0,10368), wts [10368,21736), tb [21736,25320)
constexpr int BLOB_N = 25320;   // 50640 B

__global__ __launch_bounds__(256)
void gather_inv(const unsigned short* __restrict__ yT,
                const unsigned short* __restrict__ rT,
                const unsigned short* __restrict__ spanw,  // [784][64] bf16
                const float* __restrict__ spanb,           // [784] fp32
                const float* __restrict__ g2, const float* __restrict__ b2,
                const float* __restrict__ m2, const float* __restrict__ v2,
                unsigned short* __restrict__ tT) {
  __shared__ __align__(16) unsigned short blob[BLOB_N];
  __shared__ float a2s[16], b2s[16], sbs[KK_];

  unsigned short* rs = blob;            // 224*64 shorts (swizzled rows)
  unsigned short* sws = blob + 14336;   // 64*64 shorts (swizzled rows)
  unsigned short* patchb = blob;        // [16][PB_STR] bf16 planes
  unsigned short* wts = blob + 10368;   // [49][W_TAP_STR]
  unsigned short* tb = blob + 21736;    // [224][16]

  const int tid = threadIdx.x;
  const int g = blockIdx.x;   // g fastest: 16 blocks sharing rT stripe adjacent
  const int st = blockIdx.y;  // 4-row stripe 0..13
  const int b = blockIdx.z;
  const int h0 = st * 4;
  const int wave = tid >> 6, lane = tid & 63;
  const int lq = lane & 7, lr8 = lane >> 3;
  const int quad = lane >> 4, ln = lane & 15;

  // ---- phase 0: issue patch global loads to regs (latency hides under
  //      rs/sws staging + MFMA; barrier-1 drains all vmcnt anyway) ----
  uint4 pv0[3], pv1[3];
  int poff[3];
  bool pok[3];
#pragma unroll
  for (int pi = 0; pi < 3; ++pi) {
    int e = tid + pi * 256;
    bool ok = e < 620;
    int row = e / 62, cw = e - row * 62;
    int sr = h0 + row - 3, sc = cw - 3;
    poff[pi] = row * 64 + cw;
    pok[pi] = ok;
    bool inb = ok && sr >= 0 && sr < H_ && sc >= 0 && sc < W_;
    if (inb) {
      const unsigned short* yp =
          yT + ((size_t)b * HW_ + sr * W_ + sc) * C_ + g * GC_;
      pv0[pi] = *(const uint4*)yp;
      pv1[pi] = *(const uint4*)(yp + 8);
    } else {
      pv0[pi] = make_uint4(0, 0, 0, 0);
      pv1[pi] = make_uint4(0, 0, 0, 0);
    }
  }

  // ---- phase A: stage rs (224x64) + sws (64x64) via global_load_lds ----
  {
    const unsigned short* rbase = rT + ((size_t)b * HW_ + h0 * W_) * RED_;
#pragma unroll
    for (int t = 0; t < 7; ++t) {
      int inst = wave * 7 + t;
      int row = inst * 8 + lr8;
      int qs = lq ^ (row & 7);
      gl_lds16(rbase + (size_t)row * RED_ + qs * 8, &rs[inst * 512]);
    }
    const unsigned short* swg = spanw + (size_t)(g * KK_) * RED_;
#pragma unroll
    for (int t = 0; t < 2; ++t) {
      int inst = wave * 2 + t;
      int row = inst * 8 + lr8;
      int tap = min(row, KK_ - 1);
      int qs = lq ^ (row & 7);
      gl_lds16(swg + (size_t)tap * RED_ + qs * 8, &sws[inst * 512]);
    }
    if (tid < 16) {
      int c = g * GC_ + tid;
      float sc = g2[c] * rsqrtf(v2[c] + DEV_EPS);
      a2s[tid] = sc;
      b2s[tid] = b2[c] - m2[c] * sc;
    }
    if (tid < KK_) sbs[tid] = spanb[g * KK_ + tid];
  }
  __syncthreads();  // drains vmcnt: rs/sws in LDS, patch regs loaded

  // ---- phase B: mini-MFMA  (wave = tap-tile) ----
  f32x4 wacc[14];
#pragma unroll
  for (int j = 0; j < 14; ++j)
#pragma unroll
    for (int e = 0; e < 4; ++e) wacc[j][e] = 0.f;
  {
    short8 af[2];
#pragma unroll
    for (int s = 0; s < 2; ++s) {
      int c = s * 4 + quad;
      int r = wave * 16 + ln;
      af[s] = *(const short8*)&sws[r * 64 + (c ^ (r & 7)) * 8];
    }
#pragma unroll
    for (int j = 0; j < 14; ++j) {
#pragma unroll
      for (int s = 0; s < 2; ++s) {
        int c = s * 4 + quad;
        int r = j * 16 + ln;
        short8 bf = *(const short8*)&rs[r * 64 + (c ^ (r & 7)) * 8];
        wacc[j] = __builtin_amdgcn_mfma_f32_16x16x32_bf16(af[s], bf, wacc[j],
                                                          0, 0, 0);
      }
    }
  }
  __syncthreads();  // frag reads done; rs/sws dead -> blob reusable

  // ---- phase C: write wts[tap][px] bf16 + patch bf16 planes ----
  {
#pragma unroll
    for (int r = 0; r < 4; ++r) {
      int tap = wave * 16 + quad * 4 + r;
      if (tap < KK_) {
        float sb = sbs[tap];
#pragma unroll
        for (int j = 0; j < 14; ++j)
          wts[tap * W_TAP_STR + j * 16 + ln] = bf16r(wacc[j][r] + sb);
      }
    }
#pragma unroll
    for (int pi = 0; pi < 3; ++pi) {
      if (pok[pi]) {
        int off = poff[pi];
        unsigned wv[8] = {pv0[pi].x, pv0[pi].y, pv0[pi].z, pv0[pi].w,
                          pv1[pi].x, pv1[pi].y, pv1[pi].z, pv1[pi].w};
#pragma unroll
        for (int cc = 0; cc < 8; ++cc) {
          patchb[(2 * cc) * PB_STR + off] = (unsigned short)wv[cc];
          patchb[(2 * cc + 1) * PB_STR + off] = (unsigned short)(wv[cc] >> 16);
        }
      }
    }
  }
  __syncthreads();

  // ---- phase D: 7x7 gather; item = (px4 strip s, gc) ----
#pragma unroll 1
  for (int it = 0; it < 4; ++it) {
    int item = tid + it * 256;
    if (item < 56 * 16) {
      const int gc = item & 15, s = item >> 4;
      const int r0 = s / 14, c0 = (s - r0 * 14) * 4;
      const unsigned short* patchg = patchb + gc * PB_STR + r0 * 64 + c0;
      const unsigned short* wp = wts + (r0 * 56 + c0);
      float acc0 = 0.f, acc1 = 0.f, acc2 = 0.f, acc3 = 0.f;
#pragma unroll
      for (int di = 0; di < 7; ++di) {
        const unsigned short* pp = patchg + di * 64;
        uint2 q0 = *(const uint2*)pp;
        uint2 q1 = *(const uint2*)(pp + 4);
        uint2 q2 = *(const uint2*)(pp + 8);
        unsigned uu[6] = {q0.x, q0.y, q1.x, q1.y, q2.x, q2.y};
        float pf[12];
#pragma unroll
        for (int k = 0; k < 6; ++k) {
          pf[2 * k] = __uint_as_float(uu[k] << 16);
          pf[2 * k + 1] = __uint_as_float(uu[k] & 0xffff0000u);
        }
#pragma unroll
        for (int dj = 0; dj < 7; ++dj) {
          ushort4 wv = *(const ushort4*)(wp + (di * 7 + dj) * W_TAP_STR);
          acc0 += bf2f(wv.x) * pf[dj + 0];
          acc1 += bf2f(wv.y) * pf[dj + 1];
          acc2 += bf2f(wv.z) * pf[dj + 2];
          acc3 += bf2f(wv.w) * pf[dj + 3];
        }
      }
      const float al = a2s[gc], be = b2s[gc];
      const int pxb = r0 * 56 + c0;
      tb[(pxb + 0) * 16 + gc] = bf16r(fast_tanh(al * acc0 + be));
      tb[(pxb + 1) * 16 + gc] = bf16r(fast_tanh(al * acc1 + be));
      tb[(pxb + 2) * 16 + gc] = bf16r(fast_tanh(al * acc2 + be));
      tb[(pxb + 3) * 16 + gc] = bf16r(fast_tanh(al * acc3 + be));
    }
  }
  __syncthreads();

  if (tid < 224) {
    unsigned short* dst = tT + ((size_t)b * HW_ + h0 * W_ + tid) * C_ + g * GC_;
    *(uint4*)(dst + 0) = *(const uint4*)&tb[tid * 16];
    *(uint4*)(dst + 8) = *(const uint4*)&tb[tid * 16 + 8];
  }
}

}  // namespace

extern "C" void kernel_launch(void* const* d_in, const int* in_sizes, int n_in,
                              void* d_out, int out_size, void* d_ws, size_t ws_size,
                              hipStream_t stream) {
  const float* x = (const float*)d_in[0];
  const float* w1 = (const float*)d_in[1];
  const float* b1 = (const float*)d_in[2];
  const float* bn1g = (const float*)d_in[3];
  const float* bn1b = (const float*)d_in[4];
  const float* bn1m = (const float*)d_in[5];
  const float* bn1v = (const float*)d_in[6];
  const float* red_w = (const float*)d_in[7];
  const float* red_b = (const float*)d_in[8];
  const float* rbg = (const float*)d_in[9];
  const float* rbb = (const float*)d_in[10];
  const float* rbm = (const float*)d_in[11];
  const float* rbv = (const float*)d_in[12];
  const float* span_w = (const float*)d_in[13];
  const float* span_b = (const float*)d_in[14];
  const float* bn2g = (const float*)d_in[15];
  const float* bn2b = (const float*)d_in[16];
  const float* bn2m = (const float*)d_in[17];
  const float* bn2v = (const float*)d_in[18];
  const float* w3 = (const float*)d_in[19];
  const float* b3 = (const float*)d_in[20];
  const float* bn3g = (const float*)d_in[21];
  const float* bn3b = (const float*)d_in[22];
  const float* bn3m = (const float*)d_in[23];
  const float* bn3v = (const float*)d_in[24];

  unsigned short* ws = (unsigned short*)d_ws;
  unsigned short* xT = ws;                       // 50176*256
  unsigned short* yT = xT + (size_t)NTOT * C_;   // 50176*256
  unsigned short* rT = yT + (size_t)NTOT * C_;   // 50176*64
  unsigned short* tT = rT + (size_t)NTOT * RED_; // 50176*256
  unsigned short* w1b = tT + (size_t)NTOT * C_;
  unsigned short* redb = w1b + 65536;
  unsigned short* spanb = redb + 16384;
  unsigned short* w3b = spanb + 50176;
  float* out = (float*)d_out;

  dim3 blk(256);
  wconv<<<dim3(256), blk, 0, stream>>>(w1, red_w, span_w, w3, w1b, redb, spanb, w3b);
  transpose_x<<<dim3(392), blk, 0, stream>>>(x, xT);
  // y_T = tanh(bn1(w1 @ x))
  mfma_gemm<2, 2, 256, 0><<<dim3(392, 2), blk, 0, stream>>>(
      w1b, xT, b1, bn1g, bn1b, bn1m, bn1v, nullptr, yT, C_);
  // r_T = relu(bn_red(red_w @ y))
  mfma_gemm<1, 4, 256, 1><<<dim3(196, 1), blk, 0, stream>>>(
      redb, yT, red_b, rbg, rbb, rbm, rbv, nullptr, rT, RED_);
  // t_T = tanh(bn2(involution(y; span(r))))  — span fused in, g-fastest grid
  gather_inv<<<dim3(16, 14, 16), blk, 0, stream>>>(
      yT, rT, spanb, span_b, bn2g, bn2b, bn2m, bn2v, tT);
  // out = bn3(w3 @ t) + x  (planar fp32)
  mfma_gemm<2, 2, 256, 3><<<dim3(392, 2), blk, 0, stream>>>(
      w3b, tT, b3, bn3g, bn3b, bn3m, bn3v, x, out, C_);
}

// Round 4
// 311.351 us; speedup vs baseline: 1.3264x; 1.0325x over previous
//
#include <hip/hip_runtime.h>
#include <math.h>

#define DEV_EPS 1e-5f

namespace {
constexpr int B_ = 16, C_ = 256, H_ = 56, W_ = 56, HW_ = H_ * W_;
constexpr int G_ = 16, GC_ = 16, RED_ = 64, KK_ = 49;
constexpr int NTOT = B_ * HW_;  // 50176 flattened (batch, pixel)

typedef __attribute__((ext_vector_type(8))) short short8;
typedef __attribute__((ext_vector_type(4))) float f32x4;

__device__ __forceinline__ unsigned short bf16r(float f) {
  unsigned u = __float_as_uint(f);
  u += 0x7fff + ((u >> 16) & 1);  // RNE
  return (unsigned short)(u >> 16);
}
__device__ __forceinline__ float bf2f(unsigned short s) {
  return __uint_as_float((unsigned)s << 16);
}

// tanh(x) = sign(x)*(1-e)/(1+e), e = exp(-2|x|).  ~8 VALU ops vs ~25 for
// OCML tanhf.  v_exp_f32 ~1ulp; error invisible under bf16 output rounding.
__device__ __forceinline__ float fast_tanh(float x) {
  float ax = fabsf(x);
  float e = __expf(-2.0f * ax);
  float r = (1.0f - e) * __builtin_amdgcn_rcpf(1.0f + e);
  return copysignf(r, x);
}

// async global->LDS, 16B per lane. LDS dest is wave-uniform base + lane*16
// (m104: no per-lane LDS scatter) — so any swizzle goes on the GLOBAL address.
__device__ __forceinline__ void gl_lds16(const void* g, void* l) {
  __builtin_amdgcn_global_load_lds(
      (const __attribute__((address_space(1))) unsigned int*)g,
      (__attribute__((address_space(3))) unsigned int*)l, 16, 0, 0);
}

// ---------------------------------------------------------------------------
// MFMA GEMM (template, now used only for EPI 3 = final GEMM w/ skip):
// D[m][n] = sum_k Wt[m][k] * Act[n][k].  Block = 4 waves, wave tile 64x64.
// ---------------------------------------------------------------------------
template <int WM, int WN, int KD, int EPI>
__global__ __launch_bounds__(256)
void mfma_gemm(const unsigned short* __restrict__ A,   // [M][KD] bf16
               const unsigned short* __restrict__ Act, // [NTOT][KD] bf16
               const float* __restrict__ p0,
               const float* __restrict__ bg, const float* __restrict__ bb,
               const float* __restrict__ bm, const float* __restrict__ bv,
               const float* __restrict__ xskip, void* __restrict__ outp,
               int M) {
  constexpr int BM = WM * 64, BN = WN * 64;
  __shared__ unsigned short At[BM * 64];
  __shared__ unsigned short Bt[BN * 64];
  __shared__ float aS[BM], bS[BM];

  const int tid = threadIdx.x;
  const int n0 = blockIdx.x * BN, m0 = blockIdx.y * BM;
  const int wave = tid >> 6, lane = tid & 63;
  const int wm = (WM == 2) ? (wave >> 1) : 0;
  const int wn = (WM == 2) ? (wave & 1) : wave;

  if (tid < BM) {
    int m = min(m0 + tid, M - 1);
    float sc = bg[m] * rsqrtf(bv[m] + DEV_EPS);
    aS[tid] = sc;
    bS[tid] = sc * p0[m] + bb[m] - bm[m] * sc;
  }

  f32x4 acc[4][4];
#pragma unroll
  for (int i = 0; i < 4; ++i)
#pragma unroll
    for (int j = 0; j < 4; ++j)
#pragma unroll
      for (int e = 0; e < 4; ++e) acc[i][j][e] = 0.f;

  const int lq = lane & 7;          // chunk slot within a row-octet
  const int lr8 = lane >> 3;        // row within octet group
  const int quad = lane >> 4, ln = lane & 15;

#pragma unroll 1
  for (int kt = 0; kt < KD / 64; ++kt) {
    __syncthreads();  // protect LDS from previous iteration's readers
#pragma unroll
    for (int t = 0; t < BM / 32; ++t) {
      int inst = wave * (BM / 32) + t;
      int row = inst * 8 + lr8;
      int mrow = min(m0 + row, M - 1);
      int qs = lq ^ (row & 7);
      gl_lds16(A + (size_t)mrow * KD + kt * 64 + qs * 8, &At[inst * 512]);
    }
#pragma unroll
    for (int t = 0; t < BN / 32; ++t) {
      int inst = wave * (BN / 32) + t;
      int row = inst * 8 + lr8;
      int qs = lq ^ (row & 7);
      gl_lds16(Act + (size_t)(n0 + row) * KD + kt * 64 + qs * 8, &Bt[inst * 512]);
    }
    __syncthreads();  // barrier drains vmcnt -> LDS tiles complete

#pragma unroll
    for (int s = 0; s < 2; ++s) {
      const int c = s * 4 + quad;
      short8 af[4], bf[4];
#pragma unroll
      for (int i = 0; i < 4; ++i) {
        int r = wm * 64 + i * 16 + ln;
        af[i] = *(const short8*)&At[r * 64 + (c ^ (r & 7)) * 8];
      }
#pragma unroll
      for (int j = 0; j < 4; ++j) {
        int r = wn * 64 + j * 16 + ln;
        bf[j] = *(const short8*)&Bt[r * 64 + (c ^ (r & 7)) * 8];
      }
#pragma unroll
      for (int i = 0; i < 4; ++i)
#pragma unroll
        for (int j = 0; j < 4; ++j)
          acc[i][j] = __builtin_amdgcn_mfma_f32_16x16x32_bf16(af[i], bf[j],
                                                              acc[i][j], 0, 0, 0);
    }
  }

  // epilogue: D col = lane&15 (n), row = quad*4 + reg (m)  [m89-verified]
#pragma unroll
  for (int i = 0; i < 4; ++i) {
    const int mloc = wm * 64 + i * 16 + quad * 4;
#pragma unroll
    for (int j = 0; j < 4; ++j) {
      const int np = n0 + wn * 64 + j * 16 + ln;
      if (EPI == 0 || EPI == 1) {
        ushort4 pk;
        unsigned short* pp = (unsigned short*)&pk;
#pragma unroll
        for (int r = 0; r < 4; ++r) {
          float v = aS[mloc + r] * acc[i][j][r] + bS[mloc + r];
          v = (EPI == 0) ? fast_tanh(v) : fmaxf(v, 0.f);
          pp[r] = bf16r(v);
        }
        *(ushort4*)((unsigned short*)outp + (size_t)np * M + m0 + mloc) = pk;
      } else {
        int b = np / HW_, hw = np - b * HW_;
        size_t base = ((size_t)b * C_ + m0 + mloc) * HW_ + hw;
#pragma unroll
        for (int r = 0; r < 4; ++r) {
          size_t o = base + (size_t)r * HW_;
          ((float*)outp)[o] =
              aS[mloc + r] * acc[i][j][r] + bS[mloc + r] + xskip[o];
        }
      }
    }
  }
}

// ---------------------------------------------------------------------------
// Fused GEMM1 + RED GEMM:  y_T = tanh(bn1(w1 @ x));  r_T = relu(bnr(redw @ y))
// BM=256 (all channels in-block), BN=64 px, 4 waves each own a 64-ch stripe.
// After main loop, y bounces through LDS (aliasing dead At/Bt) so the RED
// GEMM (64x64 @ k=256, 32 MFMA) runs in-block: kills the separate EPI1
// kernel (25.7 MB yT re-read + staging + launch).  redw A-frags read from
// global (32 KB, L2-resident across all 784 blocks).
// LDS: 40 KB blob + params ~2.6 KB -> 3 blocks/CU.
// ---------------------------------------------------------------------------
constexpr int YS_STR = 264;  // ushort stride for yS [64 px][256 ch + 8 pad]

__global__ __launch_bounds__(256)
void gemm_yr(const unsigned short* __restrict__ A,     // w1b [256][256]
             const unsigned short* __restrict__ Act,   // xT [NTOT][256]
             const unsigned short* __restrict__ redw,  // redb [64][256]
             const float* __restrict__ p0,             // b1
             const float* __restrict__ bg, const float* __restrict__ bb,
             const float* __restrict__ bm, const float* __restrict__ bv,
             const float* __restrict__ rp0,            // red_b
             const float* __restrict__ rbg, const float* __restrict__ rbb,
             const float* __restrict__ rbm, const float* __restrict__ rbv,
             unsigned short* __restrict__ yT, unsigned short* __restrict__ rT) {
  constexpr int BM = 256, BN = 64;
  __shared__ __align__(16) unsigned short blob2[BM * 64 + BN * 64];  // 40 KB
  __shared__ float aS[256], bS[256], aR[64], bR[64];
  unsigned short* At = blob2;            // [256][64]
  unsigned short* Bt = blob2 + BM * 64;  // [64][64]
  unsigned short* yS = blob2;            // [64][YS_STR] alias (33792 B)

  const int tid = threadIdx.x;
  const int n0 = blockIdx.x * BN;
  const int wave = tid >> 6, lane = tid & 63;
  const int lq = lane & 7, lr8 = lane >> 3;
  const int quad = lane >> 4, ln = lane & 15;

  {
    float sc = bg[tid] * rsqrtf(bv[tid] + DEV_EPS);
    aS[tid] = sc;
    bS[tid] = sc * p0[tid] + bb[tid] - bm[tid] * sc;
    if (tid < 64) {
      float s2 = rbg[tid] * rsqrtf(rbv[tid] + DEV_EPS);
      aR[tid] = s2;
      bR[tid] = s2 * rp0[tid] + rbb[tid] - rbm[tid] * s2;
    }
  }

  f32x4 acc[4][4];
#pragma unroll
  for (int i = 0; i < 4; ++i)
#pragma unroll
    for (int j = 0; j < 4; ++j)
#pragma unroll
      for (int e = 0; e < 4; ++e) acc[i][j][e] = 0.f;

#pragma unroll 1
  for (int kt = 0; kt < 4; ++kt) {
    __syncthreads();
#pragma unroll
    for (int t = 0; t < 8; ++t) {  // A: 256 rows
      int inst = wave * 8 + t;
      int row = inst * 8 + lr8;
      int qs = lq ^ (row & 7);
      gl_lds16(A + (size_t)row * 256 + kt * 64 + qs * 8, &At[inst * 512]);
    }
#pragma unroll
    for (int t = 0; t < 2; ++t) {  // B: 64 px rows
      int inst = wave * 2 + t;
      int row = inst * 8 + lr8;
      int qs = lq ^ (row & 7);
      gl_lds16(Act + (size_t)(n0 + row) * 256 + kt * 64 + qs * 8,
               &Bt[inst * 512]);
    }
    __syncthreads();

#pragma unroll
    for (int s = 0; s < 2; ++s) {
      const int c = s * 4 + quad;
      short8 af[4], bf[4];
#pragma unroll
      for (int i = 0; i < 4; ++i) {
        int r = wave * 64 + i * 16 + ln;
        af[i] = *(const short8*)&At[r * 64 + (c ^ (r & 7)) * 8];
      }
#pragma unroll
      for (int j = 0; j < 4; ++j) {
        int r = j * 16 + ln;
        bf[j] = *(const short8*)&Bt[r * 64 + (c ^ (r & 7)) * 8];
      }
#pragma unroll
      for (int i = 0; i < 4; ++i)
#pragma unroll
        for (int j = 0; j < 4; ++j)
          acc[i][j] = __builtin_amdgcn_mfma_f32_16x16x32_bf16(af[i], bf[j],
                                                              acc[i][j], 0, 0, 0);
    }
  }

  __syncthreads();  // all At/Bt readers done -> safe to alias yS

  // y epilogue: tanh(bn1) -> yT (global) + yS (LDS, [px][ch])
#pragma unroll
  for (int i = 0; i < 4; ++i) {
    const int mloc = wave * 64 + i * 16 + quad * 4;
#pragma unroll
    for (int j = 0; j < 4; ++j) {
      const int npl = j * 16 + ln;
      ushort4 pk;
      unsigned short* pp = (unsigned short*)&pk;
#pragma unroll
      for (int r = 0; r < 4; ++r) {
        float v = aS[mloc + r] * acc[i][j][r] + bS[mloc + r];
        pp[r] = bf16r(fast_tanh(v));
      }
      *(ushort4*)(yT + (size_t)(n0 + npl) * 256 + mloc) = pk;
      *(ushort4*)(yS + npl * YS_STR + mloc) = pk;
    }
  }
  __syncthreads();  // yS complete

  // RED GEMM: r[64][64px] = redw(64x256) @ yS^T ; A-frags from global (L2)
  f32x4 acc2[4];
#pragma unroll
  for (int j = 0; j < 4; ++j)
#pragma unroll
    for (int e = 0; e < 4; ++e) acc2[j][e] = 0.f;
#pragma unroll
  for (int kc = 0; kc < 8; ++kc) {
    short8 af2 =
        *(const short8*)&redw[(size_t)(wave * 16 + ln) * 256 + kc * 32 + quad * 8];
#pragma unroll
    for (int j = 0; j < 4; ++j) {
      short8 bf2 = *(const short8*)&yS[(j * 16 + ln) * YS_STR + kc * 32 + quad * 8];
      acc2[j] = __builtin_amdgcn_mfma_f32_16x16x32_bf16(af2, bf2, acc2[j], 0, 0, 0);
    }
  }
  {
    const int m2 = wave * 16 + quad * 4;
#pragma unroll
    for (int j = 0; j < 4; ++j) {
      const int np = n0 + j * 16 + ln;
      ushort4 pk;
      unsigned short* pp = (unsigned short*)&pk;
#pragma unroll
      for (int r = 0; r < 4; ++r) {
        float v = aR[m2 + r] * acc2[j][r] + bR[m2 + r];
        pp[r] = bf16r(fmaxf(v, 0.f));
      }
      *(ushort4*)(rT + (size_t)np * 64 + m2) = pk;
    }
  }
}

// ---------------------------------------------------------------------------
// x (planar fp32) -> x_T (bf16, [b*HW+px][c])  via LDS transpose.
// ---------------------------------------------------------------------------
__global__ __launch_bounds__(256)
void transpose_x(const float* __restrict__ x, unsigned short* __restrict__ xT) {
  __shared__ unsigned short tile[128 * 72];
  const int tid = threadIdx.x;
  const int px0 = blockIdx.x * 128;
  for (int p = 0; p < 4; ++p) {
    if (p) __syncthreads();
#pragma unroll
    for (int e = 0; e < 32; ++e) {
      int flat = e * 256 + tid;
      int cl = flat >> 7, pxl = flat & 127;
      int px = px0 + pxl;
      int b = px / HW_, hw = px - b * HW_;
      tile[pxl * 72 + cl] = bf16r(x[((size_t)b * C_ + p * 64 + cl) * HW_ + hw]);
    }
    __syncthreads();
    int px = tid >> 1, half = tid & 1;
    const unsigned short* src = &tile[px * 72 + half * 32];
    unsigned short* dst = &xT[(size_t)(px0 + px) * C_ + p * 64 + half * 32];
    *(uint4*)(dst + 0) = *(const uint4*)(src + 0);
    *(uint4*)(dst + 8) = *(const uint4*)(src + 8);
    *(uint4*)(dst + 16) = *(const uint4*)(src + 16);
    *(uint4*)(dst + 24) = *(const uint4*)(src + 24);
  }
}

// weights fp32 -> bf16 (all four mats)
__global__ __launch_bounds__(256)
void wconv(const float* __restrict__ w1, const float* __restrict__ rw,
           const float* __restrict__ sw, const float* __restrict__ w3,
           unsigned short* __restrict__ o1, unsigned short* __restrict__ orw,
           unsigned short* __restrict__ osw, unsigned short* __restrict__ ow3) {
  int i = blockIdx.x * 256 + threadIdx.x;
  if (i < 65536) o1[i] = bf16r(w1[i]);
  if (i < 16384) orw[i] = bf16r(rw[i]);
  if (i < 50176) osw[i] = bf16r(sw[i]);
  if (i < 65536) ow3[i] = bf16r(w3[i]);
}

// ---------------------------------------------------------------------------
// Gather v9: phase D now item = (gc-PAIR, strip): 448 items over 2 iters.
// Weight ushort4 converted once per dj serves 8 FMAs (2 gc x 4 px) instead
// of 4 — kills the duplicated weight cvt (28/di -> shared).  Live set per
// item: pf0[12]+pf1[12]+acc[8] ~ 50 VGPR (v6's 4-gc hoist blowup avoided by
// keeping converts transient inside the dj loop).
// Kept from v8: bf16 patch, aliased 51 KB blob (3 blocks/CU), T14 patch
// prefetch, g-fastest grid, fast_tanh.
// ---------------------------------------------------------------------------
constexpr int PB_STR = 648;     // ushort patch plane stride (640 used + 8 pad)
constexpr int W_TAP_STR = 232;  // ushort: 224 px + 8 pad
// blob layout (ushort offsets):
//  phase A/B: rs [0,14336), sws [14336,18432)
//  phase C/D: patch [0,10368), wts [10368,21736), tb [21736,25320)
constexpr int BLOB_N = 25320;   // 50640 B

__global__ __launch_bounds__(256)
void gather_inv(const unsigned short* __restrict__ yT,
                const unsigned short* __restrict__ rT,
                const unsigned short* __restrict__ spanw,  // [784][64] bf16
                const float* __restrict__ spanb,           // [784] fp32
                const float* __restrict__ g2, const float* __restrict__ b2,
                const float* __restrict__ m2, const float* __restrict__ v2,
                unsigned short* __restrict__ tT) {
  __shared__ __align__(16) unsigned short blob[BLOB_N];
  __shared__ float a2s[16], b2s[16], sbs[KK_];

  unsigned short* rs = blob;            // 224*64 shorts (swizzled rows)
  unsigned short* sws = blob + 14336;   // 64*64 shorts (swizzled rows)
  unsigned short* patchb = blob;        // [16][PB_STR] bf16 planes
  unsigned short* wts = blob + 10368;   // [49][W_TAP_STR]
  unsigned short* tb = blob + 21736;    // [224][16]

  const int tid = threadIdx.x;
  const int g = blockIdx.x;   // g fastest: 16 blocks sharing rT stripe adjacent
  const int st = blockIdx.y;  // 4-row stripe 0..13
  const int b = blockIdx.z;
  const int h0 = st * 4;
  const int wave = tid >> 6, lane = tid & 63;
  const int lq = lane & 7, lr8 = lane >> 3;
  const int quad = lane >> 4, ln = lane & 15;

  // ---- phase 0: issue patch global loads to regs (latency hides under
  //      rs/sws staging + MFMA; barrier-1 drains all vmcnt anyway) ----
  uint4 pv0[3], pv1[3];
  int poff[3];
  bool pok[3];
#pragma unroll
  for (int pi = 0; pi < 3; ++pi) {
    int e = tid + pi * 256;
    bool ok = e < 620;
    int row = e / 62, cw = e - row * 62;
    int sr = h0 + row - 3, sc = cw - 3;
    poff[pi] = row * 64 + cw;
    pok[pi] = ok;
    bool inb = ok && sr >= 0 && sr < H_ && sc >= 0 && sc < W_;
    if (inb) {
      const unsigned short* yp =
          yT + ((size_t)b * HW_ + sr * W_ + sc) * C_ + g * GC_;
      pv0[pi] = *(const uint4*)yp;
      pv1[pi] = *(const uint4*)(yp + 8);
    } else {
      pv0[pi] = make_uint4(0, 0, 0, 0);
      pv1[pi] = make_uint4(0, 0, 0, 0);
    }
  }

  // ---- phase A: stage rs (224x64) + sws (64x64) via global_load_lds ----
  {
    const unsigned short* rbase = rT + ((size_t)b * HW_ + h0 * W_) * RED_;
#pragma unroll
    for (int t = 0; t < 7; ++t) {
      int inst = wave * 7 + t;
      int row = inst * 8 + lr8;
      int qs = lq ^ (row & 7);
      gl_lds16(rbase + (size_t)row * RED_ + qs * 8, &rs[inst * 512]);
    }
    const unsigned short* swg = spanw + (size_t)(g * KK_) * RED_;
#pragma unroll
    for (int t = 0; t < 2; ++t) {
      int inst = wave * 2 + t;
      int row = inst * 8 + lr8;
      int tap = min(row, KK_ - 1);
      int qs = lq ^ (row & 7);
      gl_lds16(swg + (size_t)tap * RED_ + qs * 8, &sws[inst * 512]);
    }
    if (tid < 16) {
      int c = g * GC_ + tid;
      float sc = g2[c] * rsqrtf(v2[c] + DEV_EPS);
      a2s[tid] = sc;
      b2s[tid] = b2[c] - m2[c] * sc;
    }
    if (tid < KK_) sbs[tid] = spanb[g * KK_ + tid];
  }
  __syncthreads();  // drains vmcnt: rs/sws in LDS, patch regs loaded

  // ---- phase B: mini-MFMA  (wave = tap-tile) ----
  f32x4 wacc[14];
#pragma unroll
  for (int j = 0; j < 14; ++j)
#pragma unroll
    for (int e = 0; e < 4; ++e) wacc[j][e] = 0.f;
  {
    short8 af[2];
#pragma unroll
    for (int s = 0; s < 2; ++s) {
      int c = s * 4 + quad;
      int r = wave * 16 + ln;
      af[s] = *(const short8*)&sws[r * 64 + (c ^ (r & 7)) * 8];
    }
#pragma unroll
    for (int j = 0; j < 14; ++j) {
#pragma unroll
      for (int s = 0; s < 2; ++s) {
        int c = s * 4 + quad;
        int r = j * 16 + ln;
        short8 bf = *(const short8*)&rs[r * 64 + (c ^ (r & 7)) * 8];
        wacc[j] = __builtin_amdgcn_mfma_f32_16x16x32_bf16(af[s], bf, wacc[j],
                                                          0, 0, 0);
      }
    }
  }
  __syncthreads();  // frag reads done; rs/sws dead -> blob reusable

  // ---- phase C: write wts[tap][px] bf16 + patch bf16 planes ----
  {
#pragma unroll
    for (int r = 0; r < 4; ++r) {
      int tap = wave * 16 + quad * 4 + r;
      if (tap < KK_) {
        float sb = sbs[tap];
#pragma unroll
        for (int j = 0; j < 14; ++j)
          wts[tap * W_TAP_STR + j * 16 + ln] = bf16r(wacc[j][r] + sb);
      }
    }
#pragma unroll
    for (int pi = 0; pi < 3; ++pi) {
      if (pok[pi]) {
        int off = poff[pi];
        unsigned wv[8] = {pv0[pi].x, pv0[pi].y, pv0[pi].z, pv0[pi].w,
                          pv1[pi].x, pv1[pi].y, pv1[pi].z, pv1[pi].w};
#pragma unroll
        for (int cc = 0; cc < 8; ++cc) {
          patchb[(2 * cc) * PB_STR + off] = (unsigned short)wv[cc];
          patchb[(2 * cc + 1) * PB_STR + off] = (unsigned short)(wv[cc] >> 16);
        }
      }
    }
  }
  __syncthreads();

  // ---- phase D: 7x7 gather; item = (gc-pair, px4 strip) ----
#pragma unroll 1
  for (int it = 0; it < 2; ++it) {
    int item = tid + it * 256;
    if (item < 56 * 8) {
      const int gcp = item & 7, s = item >> 3;
      const int gc0 = gcp * 2;
      const int r0 = s / 14, c0 = (s - r0 * 14) * 4;
      const unsigned short* pg0 = patchb + gc0 * PB_STR + r0 * 64 + c0;
      const unsigned short* pg1 = pg0 + PB_STR;
      const unsigned short* wp = wts + (r0 * 56 + c0);
      float a00 = 0.f, a01 = 0.f, a02 = 0.f, a03 = 0.f;
      float a10 = 0.f, a11 = 0.f, a12 = 0.f, a13 = 0.f;
#pragma unroll
      for (int di = 0; di < 7; ++di) {
        const unsigned short* p0p = pg0 + di * 64;
        const unsigned short* p1p = pg1 + di * 64;
        uint2 q0 = *(const uint2*)p0p;
        uint2 q1 = *(const uint2*)(p0p + 4);
        uint2 q2 = *(const uint2*)(p0p + 8);
        uint2 u0 = *(const uint2*)p1p;
        uint2 u1 = *(const uint2*)(p1p + 4);
        uint2 u2 = *(const uint2*)(p1p + 8);
        unsigned uu0[6] = {q0.x, q0.y, q1.x, q1.y, q2.x, q2.y};
        unsigned uu1[6] = {u0.x, u0.y, u1.x, u1.y, u2.x, u2.y};
        float pf0[12], pf1[12];
#pragma unroll
        for (int k = 0; k < 6; ++k) {
          pf0[2 * k] = __uint_as_float(uu0[k] << 16);
          pf0[2 * k + 1] = __uint_as_float(uu0[k] & 0xffff0000u);
          pf1[2 * k] = __uint_as_float(uu1[k] << 16);
          pf1[2 * k + 1] = __uint_as_float(uu1[k] & 0xffff0000u);
        }
#pragma unroll
        for (int dj = 0; dj < 7; ++dj) {
          ushort4 wv = *(const ushort4*)(wp + (di * 7 + dj) * W_TAP_STR);
          float w0 = bf2f(wv.x), w1 = bf2f(wv.y), w2 = bf2f(wv.z),
                w3 = bf2f(wv.w);
          a00 += w0 * pf0[dj + 0];
          a01 += w1 * pf0[dj + 1];
          a02 += w2 * pf0[dj + 2];
          a03 += w3 * pf0[dj + 3];
          a10 += w0 * pf1[dj + 0];
          a11 += w1 * pf1[dj + 1];
          a12 += w2 * pf1[dj + 2];
          a13 += w3 * pf1[dj + 3];
        }
      }
      const int pxb = r0 * 56 + c0;
      {
        const float al = a2s[gc0], be = b2s[gc0];
        tb[(pxb + 0) * 16 + gc0] = bf16r(fast_tanh(al * a00 + be));
        tb[(pxb + 1) * 16 + gc0] = bf16r(fast_tanh(al * a01 + be));
        tb[(pxb + 2) * 16 + gc0] = bf16r(fast_tanh(al * a02 + be));
        tb[(pxb + 3) * 16 + gc0] = bf16r(fast_tanh(al * a03 + be));
      }
      {
        const float al = a2s[gc0 + 1], be = b2s[gc0 + 1];
        tb[(pxb + 0) * 16 + gc0 + 1] = bf16r(fast_tanh(al * a10 + be));
        tb[(pxb + 1) * 16 + gc0 + 1] = bf16r(fast_tanh(al * a11 + be));
        tb[(pxb + 2) * 16 + gc0 + 1] = bf16r(fast_tanh(al * a12 + be));
        tb[(pxb + 3) * 16 + gc0 + 1] = bf16r(fast_tanh(al * a13 + be));
      }
    }
  }
  __syncthreads();

  if (tid < 224) {
    unsigned short* dst = tT + ((size_t)b * HW_ + h0 * W_ + tid) * C_ + g * GC_;
    *(uint4*)(dst + 0) = *(const uint4*)&tb[tid * 16];
    *(uint4*)(dst + 8) = *(const uint4*)&tb[tid * 16 + 8];
  }
}

}  // namespace

extern "C" void kernel_launch(void* const* d_in, const int* in_sizes, int n_in,
                              void* d_out, int out_size, void* d_ws, size_t ws_size,
                              hipStream_t stream) {
  const float* x = (const float*)d_in[0];
  const float* w1 = (const float*)d_in[1];
  const float* b1 = (const float*)d_in[2];
  const float* bn1g = (const float*)d_in[3];
  const float* bn1b = (const float*)d_in[4];
  const float* bn1m = (const float*)d_in[5];
  const float* bn1v = (const float*)d_in[6];
  const float* red_w = (const float*)d_in[7];
  const float* red_b = (const float*)d_in[8];
  const float* rbg = (const float*)d_in[9];
  const float* rbb = (const float*)d_in[10];
  const float* rbm = (const float*)d_in[11];
  const float* rbv = (const float*)d_in[12];
  const float* span_w = (const float*)d_in[13];
  const float* span_b = (const float*)d_in[14];
  const float* bn2g = (const float*)d_in[15];
  const float* bn2b = (const float*)d_in[16];
  const float* bn2m = (const float*)d_in[17];
  const float* bn2v = (const float*)d_in[18];
  const float* w3 = (const float*)d_in[19];
  const float* b3 = (const float*)d_in[20];
  const float* bn3g = (const float*)d_in[21];
  const float* bn3b = (const float*)d_in[22];
  const float* bn3m = (const float*)d_in[23];
  const float* bn3v = (const float*)d_in[24];

  unsigned short* ws = (unsigned short*)d_ws;
  unsigned short* xT = ws;                       // 50176*256
  unsigned short* yT = xT + (size_t)NTOT * C_;   // 50176*256
  unsigned short* rT = yT + (size_t)NTOT * C_;   // 50176*64
  unsigned short* tT = rT + (size_t)NTOT * RED_; // 50176*256
  unsigned short* w1b = tT + (size_t)NTOT * C_;
  unsigned short* redb = w1b + 65536;
  unsigned short* spanb = redb + 16384;
  unsigned short* w3b = spanb + 50176;
  float* out = (float*)d_out;

  dim3 blk(256);
  wconv<<<dim3(256), blk, 0, stream>>>(w1, red_w, span_w, w3, w1b, redb, spanb, w3b);
  transpose_x<<<dim3(392), blk, 0, stream>>>(x, xT);
  // y_T = tanh(bn1(w1 @ x)) AND r_T = relu(bn_red(red_w @ y)) fused
  gemm_yr<<<dim3(784), blk, 0, stream>>>(
      w1b, xT, redb, b1, bn1g, bn1b, bn1m, bn1v,
      red_b, rbg, rbb, rbm, rbv, yT, rT);
  // t_T = tanh(bn2(involution(y; span(r))))  — span fused in, g-fastest grid
  gather_inv<<<dim3(16, 14, 16), blk, 0, stream>>>(
      yT, rT, spanb, span_b, bn2g, bn2b, bn2m, bn2v, tT);
  // out = bn3(w3 @ t) + x  (planar fp32)
  mfma_gemm<2, 2, 256, 3><<<dim3(392, 2), blk, 0, stream>>>(
      w3b, tT, b3, bn3g, bn3b, bn3m, bn3v, x, out, C_);
}

// Round 5
// 271.371 us; speedup vs baseline: 1.5218x; 1.1473x over previous
//
#include <hip/hip_runtime.h>
#include <math.h>

#define DEV_EPS 1e-5f

namespace {
constexpr int B_ = 16, C_ = 256, H_ = 56, W_ = 56, HW_ = H_ * W_;
constexpr int G_ = 16, GC_ = 16, RED_ = 64, KK_ = 49;
constexpr int NTOT = B_ * HW_;  // 50176 flattened (batch, pixel)

typedef __attribute__((ext_vector_type(8))) short short8;
typedef __attribute__((ext_vector_type(4))) float f32x4;

__device__ __forceinline__ unsigned short bf16r(float f) {
  unsigned u = __float_as_uint(f);
  u += 0x7fff + ((u >> 16) & 1);  // RNE
  return (unsigned short)(u >> 16);
}
__device__ __forceinline__ float bf2f(unsigned short s) {
  return __uint_as_float((unsigned)s << 16);
}

// tanh(x) = sign(x)*(1-e)/(1+e), e = exp(-2|x|).  ~8 VALU ops vs ~25 OCML.
__device__ __forceinline__ float fast_tanh(float x) {
  float ax = fabsf(x);
  float e = __expf(-2.0f * ax);
  float r = (1.0f - e) * __builtin_amdgcn_rcpf(1.0f + e);
  return copysignf(r, x);
}

// async global->LDS, 16B per lane (wave-uniform LDS base + lane*16, m104).
__device__ __forceinline__ void gl_lds16(const void* g, void* l) {
  __builtin_amdgcn_global_load_lds(
      (const __attribute__((address_space(1))) unsigned int*)g,
      (__attribute__((address_space(3))) unsigned int*)l, 16, 0, 0);
}

// ---------------------------------------------------------------------------
// gemm_yr v2:  y_T = tanh(bn1(w1 @ x));  r_T = relu(bnr(redw @ y))
//  * x-transpose FUSED: per kt, regs<-x fp32 (coalesced) -> cvt -> swizzled
//    ds_write_b32 into Bt.  transpose_x kernel + xT buffer eliminated.
//  * A (w1b, 128 KB, block-invariant) read as MFMA frags straight from
//    global/L2 — no At LDS, no A staging (same pattern the red tail already
//    used for redw).
//  * T3-min 2-phase: issue x-loads(kt+1) BEFORE compute(kt); commit after;
//    Bt double-buffered; one __syncthreads per kt.
//  LDS: blob 33 KB (Bt dbuf 16 KB during loop | yS 33 KB after) + params
//       -> 4 blocks/CU.
// ---------------------------------------------------------------------------
constexpr int YS_STR = 264;  // ushort stride for yS [64 px][256 ch + 8 pad]

__global__ __launch_bounds__(256)
void gemm_yr(const unsigned short* __restrict__ A,     // w1b [256][256]
             const float* __restrict__ x,              // planar fp32
             const unsigned short* __restrict__ redw,  // redb [64][256]
             const float* __restrict__ p0,             // b1
             const float* __restrict__ bg, const float* __restrict__ bb,
             const float* __restrict__ bm, const float* __restrict__ bv,
             const float* __restrict__ rp0,            // red_b
             const float* __restrict__ rbg, const float* __restrict__ rbb,
             const float* __restrict__ rbm, const float* __restrict__ rbv,
             unsigned short* __restrict__ yT, unsigned short* __restrict__ rT) {
  __shared__ __align__(16) unsigned short blob2[16896];  // 33792 B
  __shared__ float aS[256], bS[256], aR[64], bR[64];
  unsigned short* Bt0 = blob2;         // [64][64]
  unsigned short* Bt1 = blob2 + 4096;  // [64][64]
  unsigned short* yS = blob2;          // [64][YS_STR] alias after loop

  const int tid = threadIdx.x;
  const int n0 = blockIdx.x * 64;           // 64-px tile; HW%64==0 -> same b
  const int bi = n0 / HW_, hw0 = n0 - bi * HW_;
  const int wave = tid >> 6, lane = tid & 63;
  const int quad = lane >> 4, ln = lane & 15;
  const int c2 = tid >> 3, pxo = tid & 7;   // ch-pair, px-octet for transpose

  {
    float sc = bg[tid] * rsqrtf(bv[tid] + DEV_EPS);
    aS[tid] = sc;
    bS[tid] = sc * p0[tid] + bb[tid] - bm[tid] * sc;
    if (tid < 64) {
      float s2 = rbg[tid] * rsqrtf(rbv[tid] + DEV_EPS);
      aR[tid] = s2;
      bR[tid] = s2 * rp0[tid] + rbb[tid] - rbm[tid] * s2;
    }
  }

  float4 xa, xb, xc, xd;  // 2 channels x 8 px fp32, in flight across compute
  auto load_x = [&](int kt) {
    const float* p = x + ((size_t)bi * C_ + kt * 64 + 2 * c2) * HW_ + hw0 + pxo * 8;
    xa = *(const float4*)p;
    xb = *(const float4*)(p + 4);
    xc = *(const float4*)(p + HW_);
    xd = *(const float4*)(p + HW_ + 4);
  };
  auto commit_x = [&](unsigned short* bt) {
    float e0[8] = {xa.x, xa.y, xa.z, xa.w, xb.x, xb.y, xb.z, xb.w};
    float e1[8] = {xc.x, xc.y, xc.z, xc.w, xd.x, xd.y, xd.z, xd.w};
    const int kc = c2 >> 2;          // k-chunk of this channel pair
    const int off = 2 * (c2 & 3);    // within-chunk ushort offset (even)
#pragma unroll
    for (int i = 0; i < 8; ++i) {
      int pxl = pxo * 8 + i;
      int slot = kc ^ (i & 7);       // pxl&7 == i (pxo*8 is 8-aligned)
      unsigned pk = (unsigned)bf16r(e0[i]) | ((unsigned)bf16r(e1[i]) << 16);
      *(unsigned*)&bt[pxl * 64 + slot * 8 + off] = pk;
    }
  };

  f32x4 acc[4][4];
#pragma unroll
  for (int i = 0; i < 4; ++i)
#pragma unroll
    for (int j = 0; j < 4; ++j)
#pragma unroll
      for (int e = 0; e < 4; ++e) acc[i][j][e] = 0.f;

  load_x(0);
  commit_x(Bt0);
  __syncthreads();

#pragma unroll 1
  for (int kt = 0; kt < 4; ++kt) {
    unsigned short* cur = (kt & 1) ? Bt1 : Bt0;
    unsigned short* nxt = (kt & 1) ? Bt0 : Bt1;
    if (kt < 3) load_x(kt + 1);  // in flight during compute (T3-min)
#pragma unroll
    for (int s = 0; s < 2; ++s) {
      const int c = s * 4 + quad;
      short8 af[4], bf[4];
#pragma unroll
      for (int i = 0; i < 4; ++i)
        af[i] = *(const short8*)&A[(size_t)(wave * 64 + i * 16 + ln) * 256 +
                                   kt * 64 + c * 8];
#pragma unroll
      for (int j = 0; j < 4; ++j) {
        int r = j * 16 + ln;
        bf[j] = *(const short8*)&cur[r * 64 + (c ^ (r & 7)) * 8];
      }
#pragma unroll
      for (int i = 0; i < 4; ++i)
#pragma unroll
        for (int j = 0; j < 4; ++j)
          acc[i][j] = __builtin_amdgcn_mfma_f32_16x16x32_bf16(af[i], bf[j],
                                                              acc[i][j], 0, 0, 0);
    }
    if (kt < 3) commit_x(nxt);  // cvt+ds_write after compute (latency hidden)
    __syncthreads();
  }

  // y epilogue: tanh(bn1) -> yT (global) + yS (LDS, [px][ch])
#pragma unroll
  for (int i = 0; i < 4; ++i) {
    const int mloc = wave * 64 + i * 16 + quad * 4;
#pragma unroll
    for (int j = 0; j < 4; ++j) {
      const int npl = j * 16 + ln;
      ushort4 pk;
      unsigned short* pp = (unsigned short*)&pk;
#pragma unroll
      for (int r = 0; r < 4; ++r) {
        float v = aS[mloc + r] * acc[i][j][r] + bS[mloc + r];
        pp[r] = bf16r(fast_tanh(v));
      }
      *(ushort4*)(yT + (size_t)(n0 + npl) * 256 + mloc) = pk;
      *(ushort4*)(yS + npl * YS_STR + mloc) = pk;
    }
  }
  __syncthreads();  // yS complete

  // RED GEMM: r[64][64px] = redw(64x256) @ yS^T ; A-frags from global (L2)
  f32x4 acc2[4];
#pragma unroll
  for (int j = 0; j < 4; ++j)
#pragma unroll
    for (int e = 0; e < 4; ++e) acc2[j][e] = 0.f;
#pragma unroll
  for (int kc = 0; kc < 8; ++kc) {
    short8 af2 =
        *(const short8*)&redw[(size_t)(wave * 16 + ln) * 256 + kc * 32 + quad * 8];
#pragma unroll
    for (int j = 0; j < 4; ++j) {
      short8 bf2 = *(const short8*)&yS[(j * 16 + ln) * YS_STR + kc * 32 + quad * 8];
      acc2[j] = __builtin_amdgcn_mfma_f32_16x16x32_bf16(af2, bf2, acc2[j], 0, 0, 0);
    }
  }
  {
    const int m2 = wave * 16 + quad * 4;
#pragma unroll
    for (int j = 0; j < 4; ++j) {
      const int np = n0 + j * 16 + ln;
      ushort4 pk;
      unsigned short* pp = (unsigned short*)&pk;
#pragma unroll
      for (int r = 0; r < 4; ++r) {
        float v = aR[m2 + r] * acc2[j][r] + bR[m2 + r];
        pp[r] = bf16r(fmaxf(v, 0.f));
      }
      *(ushort4*)(rT + (size_t)np * 64 + m2) = pk;
    }
  }
}

// ---------------------------------------------------------------------------
// gemm_out: out = bn3(w3 @ t) + x  (planar fp32).
//  * A (w3b) frags from global/L2 (no At LDS).
//  * Bt (tT) double-buffered via gl_lds16; stage(kt+1) issued BEFORE
//    compute(kt) -> loads in flight under MFMA (T3-min); one barrier per kt.
//  LDS 32.5 KB -> 4 blocks/CU.
// ---------------------------------------------------------------------------
__global__ __launch_bounds__(256)
void gemm_out(const unsigned short* __restrict__ A,    // w3b [256][256]
              const unsigned short* __restrict__ Act,  // tT [NTOT][256]
              const float* __restrict__ p0,
              const float* __restrict__ bg, const float* __restrict__ bb,
              const float* __restrict__ bm, const float* __restrict__ bv,
              const float* __restrict__ xskip, float* __restrict__ out) {
  __shared__ __align__(16) unsigned short Bt[2][128 * 64];  // 32 KB
  __shared__ float aS[128], bS[128];

  const int tid = threadIdx.x;
  const int n0 = blockIdx.x * 128, m0 = blockIdx.y * 128;
  const int wave = tid >> 6, lane = tid & 63;
  const int wm = wave >> 1, wn = wave & 1;
  const int lq = lane & 7, lr8 = lane >> 3;
  const int quad = lane >> 4, ln = lane & 15;

  if (tid < 128) {
    int m = m0 + tid;
    float sc = bg[m] * rsqrtf(bv[m] + DEV_EPS);
    aS[tid] = sc;
    bS[tid] = sc * p0[m] + bb[m] - bm[m] * sc;
  }

  f32x4 acc[4][4];
#pragma unroll
  for (int i = 0; i < 4; ++i)
#pragma unroll
    for (int j = 0; j < 4; ++j)
#pragma unroll
      for (int e = 0; e < 4; ++e) acc[i][j][e] = 0.f;

  // prologue: stage Bt[0] for kt=0
#pragma unroll
  for (int t = 0; t < 4; ++t) {
    int inst = wave * 4 + t;
    int row = inst * 8 + lr8;
    int qs = lq ^ (row & 7);
    gl_lds16(Act + (size_t)(n0 + row) * 256 + qs * 8, &Bt[0][inst * 512]);
  }
  __syncthreads();

#pragma unroll 1
  for (int kt = 0; kt < 4; ++kt) {
    const int cur = kt & 1;
    if (kt < 3) {  // issue next-tile staging BEFORE compute
#pragma unroll
      for (int t = 0; t < 4; ++t) {
        int inst = wave * 4 + t;
        int row = inst * 8 + lr8;
        int qs = lq ^ (row & 7);
        gl_lds16(Act + (size_t)(n0 + row) * 256 + (kt + 1) * 64 + qs * 8,
                 &Bt[cur ^ 1][inst * 512]);
      }
    }
#pragma unroll
    for (int s = 0; s < 2; ++s) {
      const int c = s * 4 + quad;
      short8 af[4], bf[4];
#pragma unroll
      for (int i = 0; i < 4; ++i)
        af[i] = *(const short8*)&A[(size_t)(m0 + wm * 64 + i * 16 + ln) * 256 +
                                   kt * 64 + c * 8];
#pragma unroll
      for (int j = 0; j < 4; ++j) {
        int r = wn * 64 + j * 16 + ln;
        bf[j] = *(const short8*)&Bt[cur][r * 64 + (c ^ (r & 7)) * 8];
      }
#pragma unroll
      for (int i = 0; i < 4; ++i)
#pragma unroll
        for (int j = 0; j < 4; ++j)
          acc[i][j] = __builtin_amdgcn_mfma_f32_16x16x32_bf16(af[i], bf[j],
                                                              acc[i][j], 0, 0, 0);
    }
    __syncthreads();  // drains staged loads; next kt reads the other buffer
  }

  // epilogue: bn3 + x skip -> planar fp32
#pragma unroll
  for (int i = 0; i < 4; ++i) {
    const int mloc = wm * 64 + i * 16 + quad * 4;
#pragma unroll
    for (int j = 0; j < 4; ++j) {
      const int np = n0 + wn * 64 + j * 16 + ln;
      int b = np / HW_, hw = np - b * HW_;
      size_t base = ((size_t)b * C_ + m0 + mloc) * HW_ + hw;
#pragma unroll
      for (int r = 0; r < 4; ++r) {
        size_t o = base + (size_t)r * HW_;
        out[o] = aS[mloc + r] * acc[i][j][r] + bS[mloc + r] + xskip[o];
      }
    }
  }
}

// weights fp32 -> bf16 (all four mats)
__global__ __launch_bounds__(256)
void wconv(const float* __restrict__ w1, const float* __restrict__ rw,
           const float* __restrict__ sw, const float* __restrict__ w3,
           unsigned short* __restrict__ o1, unsigned short* __restrict__ orw,
           unsigned short* __restrict__ osw, unsigned short* __restrict__ ow3) {
  int i = blockIdx.x * 256 + threadIdx.x;
  if (i < 65536) o1[i] = bf16r(w1[i]);
  if (i < 16384) orw[i] = bf16r(rw[i]);
  if (i < 50176) osw[i] = bf16r(sw[i]);
  if (i < 65536) ow3[i] = bf16r(w3[i]);
}

// ---------------------------------------------------------------------------
// Gather v9 (unchanged): span GEMM fused; bf16 patch; aliased 51 KB blob
// (3 blocks/CU); T14 patch prefetch; g-fastest grid; fast_tanh; phase-D
// gc-pair weight sharing.
// ---------------------------------------------------------------------------
constexpr int PB_STR = 648;     // ushort patch plane stride (640 used + 8 pad)
constexpr int W_TAP_STR = 232;  // ushort: 224 px + 8 pad
constexpr int BLOB_N = 25320;   // 50640 B

__global__ __launch_bounds__(256)
void gather_inv(const unsigned short* __restrict__ yT,
                const unsigned short* __restrict__ rT,
                const unsigned short* __restrict__ spanw,  // [784][64] bf16
                const float* __restrict__ spanb,           // [784] fp32
                const float* __restrict__ g2, const float* __restrict__ b2,
                const float* __restrict__ m2, const float* __restrict__ v2,
                unsigned short* __restrict__ tT) {
  __shared__ __align__(16) unsigned short blob[BLOB_N];
  __shared__ float a2s[16], b2s[16], sbs[KK_];

  unsigned short* rs = blob;            // 224*64 shorts (swizzled rows)
  unsigned short* sws = blob + 14336;   // 64*64 shorts (swizzled rows)
  unsigned short* patchb = blob;        // [16][PB_STR] bf16 planes
  unsigned short* wts = blob + 10368;   // [49][W_TAP_STR]
  unsigned short* tb = blob + 21736;    // [224][16]

  const int tid = threadIdx.x;
  const int g = blockIdx.x;   // g fastest: 16 blocks sharing rT stripe adjacent
  const int st = blockIdx.y;  // 4-row stripe 0..13
  const int b = blockIdx.z;
  const int h0 = st * 4;
  const int wave = tid >> 6, lane = tid & 63;
  const int lq = lane & 7, lr8 = lane >> 3;
  const int quad = lane >> 4, ln = lane & 15;

  // ---- phase 0: issue patch global loads to regs ----
  uint4 pv0[3], pv1[3];
  int poff[3];
  bool pok[3];
#pragma unroll
  for (int pi = 0; pi < 3; ++pi) {
    int e = tid + pi * 256;
    bool ok = e < 620;
    int row = e / 62, cw = e - row * 62;
    int sr = h0 + row - 3, sc = cw - 3;
    poff[pi] = row * 64 + cw;
    pok[pi] = ok;
    bool inb = ok && sr >= 0 && sr < H_ && sc >= 0 && sc < W_;
    if (inb) {
      const unsigned short* yp =
          yT + ((size_t)b * HW_ + sr * W_ + sc) * C_ + g * GC_;
      pv0[pi] = *(const uint4*)yp;
      pv1[pi] = *(const uint4*)(yp + 8);
    } else {
      pv0[pi] = make_uint4(0, 0, 0, 0);
      pv1[pi] = make_uint4(0, 0, 0, 0);
    }
  }

  // ---- phase A: stage rs (224x64) + sws (64x64) via global_load_lds ----
  {
    const unsigned short* rbase = rT + ((size_t)b * HW_ + h0 * W_) * RED_;
#pragma unroll
    for (int t = 0; t < 7; ++t) {
      int inst = wave * 7 + t;
      int row = inst * 8 + lr8;
      int qs = lq ^ (row & 7);
      gl_lds16(rbase + (size_t)row * RED_ + qs * 8, &rs[inst * 512]);
    }
    const unsigned short* swg = spanw + (size_t)(g * KK_) * RED_;
#pragma unroll
    for (int t = 0; t < 2; ++t) {
      int inst = wave * 2 + t;
      int row = inst * 8 + lr8;
      int tap = min(row, KK_ - 1);
      int qs = lq ^ (row & 7);
      gl_lds16(swg + (size_t)tap * RED_ + qs * 8, &sws[inst * 512]);
    }
    if (tid < 16) {
      int c = g * GC_ + tid;
      float sc = g2[c] * rsqrtf(v2[c] + DEV_EPS);
      a2s[tid] = sc;
      b2s[tid] = b2[c] - m2[c] * sc;
    }
    if (tid < KK_) sbs[tid] = spanb[g * KK_ + tid];
  }
  __syncthreads();  // drains vmcnt: rs/sws in LDS, patch regs loaded

  // ---- phase B: mini-MFMA  (wave = tap-tile) ----
  f32x4 wacc[14];
#pragma unroll
  for (int j = 0; j < 14; ++j)
#pragma unroll
    for (int e = 0; e < 4; ++e) wacc[j][e] = 0.f;
  {
    short8 af[2];
#pragma unroll
    for (int s = 0; s < 2; ++s) {
      int c = s * 4 + quad;
      int r = wave * 16 + ln;
      af[s] = *(const short8*)&sws[r * 64 + (c ^ (r & 7)) * 8];
    }
#pragma unroll
    for (int j = 0; j < 14; ++j) {
#pragma unroll
      for (int s = 0; s < 2; ++s) {
        int c = s * 4 + quad;
        int r = j * 16 + ln;
        short8 bf = *(const short8*)&rs[r * 64 + (c ^ (r & 7)) * 8];
        wacc[j] = __builtin_amdgcn_mfma_f32_16x16x32_bf16(af[s], bf, wacc[j],
                                                          0, 0, 0);
      }
    }
  }
  __syncthreads();  // frag reads done; rs/sws dead -> blob reusable

  // ---- phase C: write wts[tap][px] bf16 + patch bf16 planes ----
  {
#pragma unroll
    for (int r = 0; r < 4; ++r) {
      int tap = wave * 16 + quad * 4 + r;
      if (tap < KK_) {
        float sb = sbs[tap];
#pragma unroll
        for (int j = 0; j < 14; ++j)
          wts[tap * W_TAP_STR + j * 16 + ln] = bf16r(wacc[j][r] + sb);
      }
    }
#pragma unroll
    for (int pi = 0; pi < 3; ++pi) {
      if (pok[pi]) {
        int off = poff[pi];
        unsigned wv[8] = {pv0[pi].x, pv0[pi].y, pv0[pi].z, pv0[pi].w,
                          pv1[pi].x, pv1[pi].y, pv1[pi].z, pv1[pi].w};
#pragma unroll
        for (int cc = 0; cc < 8; ++cc) {
          patchb[(2 * cc) * PB_STR + off] = (unsigned short)wv[cc];
          patchb[(2 * cc + 1) * PB_STR + off] = (unsigned short)(wv[cc] >> 16);
        }
      }
    }
  }
  __syncthreads();

  // ---- phase D: 7x7 gather; item = (gc-pair, px4 strip) ----
#pragma unroll 1
  for (int it = 0; it < 2; ++it) {
    int item = tid + it * 256;
    if (item < 56 * 8) {
      const int gcp = item & 7, s = item >> 3;
      const int gc0 = gcp * 2;
      const int r0 = s / 14, c0 = (s - r0 * 14) * 4;
      const unsigned short* pg0 = patchb + gc0 * PB_STR + r0 * 64 + c0;
      const unsigned short* pg1 = pg0 + PB_STR;
      const unsigned short* wp = wts + (r0 * 56 + c0);
      float a00 = 0.f, a01 = 0.f, a02 = 0.f, a03 = 0.f;
      float a10 = 0.f, a11 = 0.f, a12 = 0.f, a13 = 0.f;
#pragma unroll
      for (int di = 0; di < 7; ++di) {
        const unsigned short* p0p = pg0 + di * 64;
        const unsigned short* p1p = pg1 + di * 64;
        uint2 q0 = *(const uint2*)p0p;
        uint2 q1 = *(const uint2*)(p0p + 4);
        uint2 q2 = *(const uint2*)(p0p + 8);
        uint2 u0 = *(const uint2*)p1p;
        uint2 u1 = *(const uint2*)(p1p + 4);
        uint2 u2 = *(const uint2*)(p1p + 8);
        unsigned uu0[6] = {q0.x, q0.y, q1.x, q1.y, q2.x, q2.y};
        unsigned uu1[6] = {u0.x, u0.y, u1.x, u1.y, u2.x, u2.y};
        float pf0[12], pf1[12];
#pragma unroll
        for (int k = 0; k < 6; ++k) {
          pf0[2 * k] = __uint_as_float(uu0[k] << 16);
          pf0[2 * k + 1] = __uint_as_float(uu0[k] & 0xffff0000u);
          pf1[2 * k] = __uint_as_float(uu1[k] << 16);
          pf1[2 * k + 1] = __uint_as_float(uu1[k] & 0xffff0000u);
        }
#pragma unroll
        for (int dj = 0; dj < 7; ++dj) {
          ushort4 wv = *(const ushort4*)(wp + (di * 7 + dj) * W_TAP_STR);
          float w0 = bf2f(wv.x), w1 = bf2f(wv.y), w2 = bf2f(wv.z),
                w3 = bf2f(wv.w);
          a00 += w0 * pf0[dj + 0];
          a01 += w1 * pf0[dj + 1];
          a02 += w2 * pf0[dj + 2];
          a03 += w3 * pf0[dj + 3];
          a10 += w0 * pf1[dj + 0];
          a11 += w1 * pf1[dj + 1];
          a12 += w2 * pf1[dj + 2];
          a13 += w3 * pf1[dj + 3];
        }
      }
      const int pxb = r0 * 56 + c0;
      {
        const float al = a2s[gc0], be = b2s[gc0];
        tb[(pxb + 0) * 16 + gc0] = bf16r(fast_tanh(al * a00 + be));
        tb[(pxb + 1) * 16 + gc0] = bf16r(fast_tanh(al * a01 + be));
        tb[(pxb + 2) * 16 + gc0] = bf16r(fast_tanh(al * a02 + be));
        tb[(pxb + 3) * 16 + gc0] = bf16r(fast_tanh(al * a03 + be));
      }
      {
        const float al = a2s[gc0 + 1], be = b2s[gc0 + 1];
        tb[(pxb + 0) * 16 + gc0 + 1] = bf16r(fast_tanh(al * a10 + be));
        tb[(pxb + 1) * 16 + gc0 + 1] = bf16r(fast_tanh(al * a11 + be));
        tb[(pxb + 2) * 16 + gc0 + 1] = bf16r(fast_tanh(al * a12 + be));
        tb[(pxb + 3) * 16 + gc0 + 1] = bf16r(fast_tanh(al * a13 + be));
      }
    }
  }
  __syncthreads();

  if (tid < 224) {
    unsigned short* dst = tT + ((size_t)b * HW_ + h0 * W_ + tid) * C_ + g * GC_;
    *(uint4*)(dst + 0) = *(const uint4*)&tb[tid * 16];
    *(uint4*)(dst + 8) = *(const uint4*)&tb[tid * 16 + 8];
  }
}

}  // namespace

extern "C" void kernel_launch(void* const* d_in, const int* in_sizes, int n_in,
                              void* d_out, int out_size, void* d_ws, size_t ws_size,
                              hipStream_t stream) {
  const float* x = (const float*)d_in[0];
  const float* w1 = (const float*)d_in[1];
  const float* b1 = (const float*)d_in[2];
  const float* bn1g = (const float*)d_in[3];
  const float* bn1b = (const float*)d_in[4];
  const float* bn1m = (const float*)d_in[5];
  const float* bn1v = (const float*)d_in[6];
  const float* red_w = (const float*)d_in[7];
  const float* red_b = (const float*)d_in[8];
  const float* rbg = (const float*)d_in[9];
  const float* rbb = (const float*)d_in[10];
  const float* rbm = (const float*)d_in[11];
  const float* rbv = (const float*)d_in[12];
  const float* span_w = (const float*)d_in[13];
  const float* span_b = (const float*)d_in[14];
  const float* bn2g = (const float*)d_in[15];
  const float* bn2b = (const float*)d_in[16];
  const float* bn2m = (const float*)d_in[17];
  const float* bn2v = (const float*)d_in[18];
  const float* w3 = (const float*)d_in[19];
  const float* b3 = (const float*)d_in[20];
  const float* bn3g = (const float*)d_in[21];
  const float* bn3b = (const float*)d_in[22];
  const float* bn3m = (const float*)d_in[23];
  const float* bn3v = (const float*)d_in[24];

  unsigned short* ws = (unsigned short*)d_ws;
  unsigned short* xT = ws;                       // (unused slot, kept layout)
  unsigned short* yT = xT + (size_t)NTOT * C_;   // 50176*256
  unsigned short* rT = yT + (size_t)NTOT * C_;   // 50176*64
  unsigned short* tT = rT + (size_t)NTOT * RED_; // 50176*256
  unsigned short* w1b = tT + (size_t)NTOT * C_;
  unsigned short* redb = w1b + 65536;
  unsigned short* spanb = redb + 16384;
  unsigned short* w3b = spanb + 50176;
  float* out = (float*)d_out;
  (void)xT;

  dim3 blk(256);
  wconv<<<dim3(256), blk, 0, stream>>>(w1, red_w, span_w, w3, w1b, redb, spanb, w3b);
  // y_T = tanh(bn1(w1 @ x)) AND r_T = relu(bn_red(red_w @ y)); x-transpose fused
  gemm_yr<<<dim3(784), blk, 0, stream>>>(
      w1b, x, redb, b1, bn1g, bn1b, bn1m, bn1v,
      red_b, rbg, rbb, rbm, rbv, yT, rT);
  // t_T = tanh(bn2(involution(y; span(r))))  — span fused in, g-fastest grid
  gather_inv<<<dim3(16, 14, 16), blk, 0, stream>>>(
      yT, rT, spanb, span_b, bn2g, bn2b, bn2m, bn2v, tT);
  // out = bn3(w3 @ t) + x  (planar fp32), dbuf-pipelined
  gemm_out<<<dim3(392, 2), blk, 0, stream>>>(
      w3b, tT, b3, bn3g, bn3b, bn3m, bn3v, x, out);
}